// Round 3
// baseline (430.458 us; speedup 1.0000x reference)
//
#include <hip/hip_runtime.h>

#define NH 16
#define HD 64
#define WIN 256
#define BB 2
#define SS 4096
#define EE 1024

typedef __attribute__((ext_vector_type(8))) short short8;
typedef __attribute__((ext_vector_type(4))) float floatx4;
typedef __attribute__((ext_vector_type(4))) unsigned short ushort4v;

__device__ inline unsigned short f2bf(float f) {
    unsigned u = __builtin_bit_cast(unsigned, f);
    u += 0x7fffu + ((u >> 16) & 1u);
    return (unsigned short)(u >> 16);
}

// ---------------- pass 0: f32 -> bf16 convert of X and W's into d_out scratch
__global__ __launch_bounds__(256)
void cvt_kernel(const float* __restrict__ X,
                const float* __restrict__ W0,
                const float* __restrict__ W1,
                const float* __restrict__ W2,
                unsigned short* __restrict__ out)
{
    size_t idx = (size_t)blockIdx.x * 256 + threadIdx.x;   // float4 index
    const size_t X4 = 2097152, W4 = 262144;                // float4 counts
    const float* src; unsigned short* dst; size_t off;
    if (idx < X4)                { src = X;  dst = out;            off = idx; }
    else if (idx < X4 + W4)      { src = W0; dst = out + 8388608;  off = idx - X4; }
    else if (idx < X4 + 2 * W4)  { src = W1; dst = out + 9437184;  off = idx - X4 - W4; }
    else                         { src = W2; dst = out + 10485760; off = idx - X4 - 2 * W4; }
    float4 v = ((const float4*)src)[off];
    ushort4 u;
    u.x = f2bf(v.x); u.y = f2bf(v.y); u.z = f2bf(v.z); u.w = f2bf(v.w);
    ((ushort4*)dst)[off] = u;
}

// ---------------- pass 1: bf16 GEMM, BM=256 BN=128 BK=64.
// Grid 768 blocks = exactly 3 blocks/CU (48 KB LDS each) => single occupancy
// round, no tail (previous 1536-block config ran 1.5 rounds = ~25% idle).
// Per-wave structure (64x64 out, acc[4][4], 16x16x32 MFMA, global_load_lds
// staging) is byte-identical to the proven 63.5us kernel; only the wave grid
// (4x2) and epilogue indexing changed.
__global__ __launch_bounds__(512, 6)
void qkv_gemm4(const unsigned short* __restrict__ Xb,
               const unsigned short* __restrict__ WbAll,
               const float* __restrict__ b0,
               const float* __restrict__ b1,
               const float* __restrict__ b2,
               unsigned short* __restrict__ Qo,
               unsigned short* __restrict__ Ko,
               unsigned short* __restrict__ Vo)
{
    const int id = blockIdx.x;                // 0..767
    const int xcd = id & 7;
    const int rest = id >> 3;                 // 0..95
    const int mtile = xcd + 8 * (rest & 3);   // 0..31, mtile%8 == xcd (L2 locality)
    const int nm = rest >> 2;                 // 0..23
    const int ntile = nm & 7;                 // 0..7
    const int mode = nm >> 3;                 // 0..2

    const unsigned short* Wm = WbAll + (size_t)mode * 1048576;
    const float* bm = (mode == 0) ? b0 : (mode == 1) ? b1 : b2;
    unsigned short* outp = (mode == 0) ? Qo : (mode == 1) ? Ko : Vo;

    const int m0 = mtile * 256;
    const int n0 = ntile * 128;
    const int t = threadIdx.x;                // 0..511
    const int lane = t & 63;
    const int wv = t >> 6;                    // 0..7
    const int wm = wv >> 1;                   // 0..3 (64-row group)
    const int wn = wv & 1;                    // 0..1 (64-col group)
    const int lg = lane >> 4, lc = lane & 15;

    __shared__ __attribute__((aligned(16))) unsigned short smem[24576];  // 48 KB
    unsigned short* As[2] = { smem, smem + 8192 };          // 256x32 each
    unsigned short* Bs[2] = { smem + 16384, smem + 20480 }; // 128x32 each

    const int srow = lane >> 2;               // 0..15
    const int scol = (lane & 3) * 8;

    floatx4 acc[4][4];
#pragma unroll
    for (int i = 0; i < 4; ++i)
#pragma unroll
        for (int j = 0; j < 4; ++j)
            acc[i][j] = (floatx4)0.0f;

    for (int kt = 0; kt < EE; kt += 64) {
        if (kt) __syncthreads();
#pragma unroll
        for (int half = 0; half < 2; ++half) {
#pragma unroll
            for (int seg = 0; seg < 2; ++seg) {      // A: 8 waves x 2 segs = 256 rows
                int r0 = wv * 32 + seg * 16;
                const unsigned short* asrc =
                    Xb + (size_t)(m0 + r0 + srow) * EE + kt + half * 32 + scol;
                __builtin_amdgcn_global_load_lds(
                    (const __attribute__((address_space(1))) unsigned int*)asrc,
                    (__attribute__((address_space(3))) unsigned int*)&As[half][r0 * 32], 16, 0, 0);
            }
            {                                        // B: 8 waves x 1 seg = 128 rows
                int rb = wv * 16;
                const unsigned short* bsrc =
                    Wm + (size_t)(n0 + rb + srow) * EE + kt + half * 32 + scol;
                __builtin_amdgcn_global_load_lds(
                    (const __attribute__((address_space(1))) unsigned int*)bsrc,
                    (__attribute__((address_space(3))) unsigned int*)&Bs[half][rb * 32], 16, 0, 0);
            }
        }
        __syncthreads();

#pragma unroll
        for (int half = 0; half < 2; ++half) {
            short8 af[4], bfr[4];
#pragma unroll
            for (int mt = 0; mt < 4; ++mt)
                af[mt] = *(const short8*)(&As[half][(wm * 64 + mt * 16 + lc) * 32 + lg * 8]);
#pragma unroll
            for (int nt = 0; nt < 4; ++nt)
                bfr[nt] = *(const short8*)(&Bs[half][(wn * 64 + nt * 16 + lc) * 32 + lg * 8]);
#pragma unroll
            for (int mt = 0; mt < 4; ++mt)
#pragma unroll
                for (int nt = 0; nt < 4; ++nt)
                    acc[mt][nt] = __builtin_amdgcn_mfma_f32_16x16x32_bf16(
                        af[mt], bfr[nt], acc[mt][nt], 0, 0, 0);
        }
    }

    const float qscale = (mode == 0) ? 0.125f : 1.0f;
#pragma unroll
    for (int p = 0; p < 2; ++p) {
        __syncthreads();
        if (mode < 2) {
            const int CST = 136;
            if ((wm >> 1) == p) {     // wm 0,1 -> pass 0 (rows 0..127); 2,3 -> pass 1
#pragma unroll
                for (int nt = 0; nt < 4; ++nt) {
                    float bias = bm[n0 + wn * 64 + nt * 16 + lc];
#pragma unroll
                    for (int mt = 0; mt < 4; ++mt)
#pragma unroll
                        for (int r = 0; r < 4; ++r) {
                            int ml = (wm & 1) * 64 + mt * 16 + lg * 4 + r;  // 0..127
                            int nl = wn * 64 + nt * 16 + lc;                // 0..127
                            smem[ml * CST + nl] = f2bf((acc[mt][nt][r] + bias) * qscale);
                        }
                }
            }
            __syncthreads();
#pragma unroll
            for (int q = 0; q < 4; ++q) {           // 128 rows x 16 j = 2048 uint4
                int c = q * 512 + t;
                int row = c >> 4;
                int j = c & 15;
                uint4 val = *(const uint4*)(&smem[row * CST + j * 8]);
                int m = m0 + p * 128 + row;
                int bb = m >> 12, s = m & (SS - 1);
                int n = n0 + j * 8;
                int hh = n >> 6, dd = n & 63;
                *(uint4*)(outp + (((size_t)bb * NH + hh) * SS + s) * HD + dd) = val;
            }
        } else {
            const int CSTm = 264;
            if (wn == p) {            // n-half p writes its 64 cols, transposed [n][m]
#pragma unroll
                for (int nt = 0; nt < 4; ++nt) {
                    float bias = bm[n0 + p * 64 + nt * 16 + lc];
#pragma unroll
                    for (int mt = 0; mt < 4; ++mt) {
                        ushort4v pk;
#pragma unroll
                        for (int r = 0; r < 4; ++r)
                            pk[r] = f2bf(acc[mt][nt][r] + bias);
                        int nl = nt * 16 + lc;               // 0..63
                        int col = wm * 64 + mt * 16 + lg * 4; // 0..255
                        *(ushort4v*)(&smem[nl * CSTm + col]) = pk;
                    }
                }
            }
            __syncthreads();
#pragma unroll
            for (int q = 0; q < 4; ++q) {           // 64 rows x 32 j = 2048 uint4
                int c = q * 512 + t;
                int row = c >> 5;
                int j = c & 31;
                uint4 val = *(const uint4*)(&smem[row * CSTm + j * 8]);
                int n = n0 + p * 64 + row;
                int hh = n >> 6, dd = n & 63;
                int m = m0 + j * 8;
                int bb = m >> 12, s = m & (SS - 1);
                *(uint4*)(outp + (((size_t)bb * NH + hh) * HD + dd) * SS + s) = val;
            }
        }
    }
}

// ---------------- pass 2: banded flash attention, unnormalized streaming softmax
// (round-0 proven version: QBLK=128, 4 waves)
__global__ __launch_bounds__(256, 2)
void swa_kernel(const unsigned short* __restrict__ Qp_,
                const unsigned short* __restrict__ Kp_,
                const unsigned short* __restrict__ Vp_,
                float* __restrict__ outp)
{
    const int h = blockIdx.x;
    const int q0 = blockIdx.y * 128;
    const int b = blockIdx.z;
    const int t = threadIdx.x, lane = t & 63, wv = t >> 6;
    const int lg = lane >> 4, lc = lane & 15;
    const size_t bh = (size_t)b * NH + h;
    const unsigned short* Qp = Qp_ + bh * (size_t)SS * HD;
    const unsigned short* Kp = Kp_ + bh * (size_t)SS * HD;
    const unsigned short* Vp = Vp_ + bh * (size_t)HD * SS;
    const int qbase = q0 + wv * 32;

    short8 qf[2][2];
#pragma unroll
    for (int rt = 0; rt < 2; ++rt)
#pragma unroll
        for (int hh = 0; hh < 2; ++hh)
            qf[rt][hh] = *(const short8*)(Qp + (size_t)(qbase + rt * 16 + lc) * HD + hh * 32 + lg * 8);

    floatx4 o[2][4];
    float lsum[2][4];
#pragma unroll
    for (int rt = 0; rt < 2; ++rt)
#pragma unroll
        for (int i = 0; i < 4; ++i) { o[rt][i] = (floatx4)0.0f; lsum[rt][i] = 0.0f; }

    __shared__ __attribute__((aligned(16))) unsigned short kvs[2][2][4096];
    __shared__ __attribute__((aligned(16))) unsigned short Ps[4][2][16][72];

    const int kbeg = (q0 >= WIN) ? (q0 - WIN) : 0;
    const int kend = (q0 + 128 + WIN <= SS) ? (q0 + 128 + WIN) : SS;

    const int sr = lane >> 3;
    const int sj = lane & 7;
    const int swz = (sj ^ sr) * 8;

#define STAGE(buf, k0_)                                                              \
    {                                                                                \
        _Pragma("unroll")                                                            \
        for (int i = 0; i < 2; ++i) {                                                \
            int rbase = 16 * wv + i * 8;                                             \
            const unsigned short* ks = Kp + (size_t)((k0_) + rbase + sr) * HD + swz; \
            const unsigned short* vs = Vp + (size_t)(rbase + sr) * SS + (k0_) + swz; \
            __builtin_amdgcn_global_load_lds(                                        \
                (const __attribute__((address_space(1))) unsigned int*)ks,           \
                (__attribute__((address_space(3))) unsigned int*)&kvs[buf][0][rbase * 64], 16, 0, 0); \
            __builtin_amdgcn_global_load_lds(                                        \
                (const __attribute__((address_space(1))) unsigned int*)vs,           \
                (__attribute__((address_space(3))) unsigned int*)&kvs[buf][1][rbase * 64], 16, 0, 0); \
        }                                                                            \
    }

    STAGE(0, kbeg)

    int cur = 0;
    for (int k0 = kbeg; k0 < kend; k0 += 64, cur ^= 1) {
        __syncthreads();
        bool active = (k0 + 63 >= qbase - WIN) && (k0 <= qbase + 31 + WIN);
        short8 kc[4][2], vf[4][2];
        if (active) {
#pragma unroll
            for (int nt = 0; nt < 4; ++nt)
#pragma unroll
                for (int hh = 0; hh < 2; ++hh) {
                    int row = nt * 16 + lc;
                    kc[nt][hh] = *(const short8*)(&kvs[cur][0][row * 64 + (((hh * 4 + lg) ^ (row & 7)) * 8)]);
                    vf[nt][hh] = *(const short8*)(&kvs[cur][1][row * 64 + (((hh * 4 + lg) ^ (row & 7)) * 8)]);
                }
        }
        if (k0 + 64 < kend) STAGE(cur ^ 1, k0 + 64)
        if (!active) continue;

        bool fullband = (k0 >= qbase - 225) && (k0 <= qbase + 193);

        floatx4 sc[2][4];
#pragma unroll
        for (int rt = 0; rt < 2; ++rt)
#pragma unroll
            for (int nt = 0; nt < 4; ++nt) {
                floatx4 z = (floatx4)0.0f;
                z = __builtin_amdgcn_mfma_f32_16x16x32_bf16(qf[rt][0], kc[nt][0], z, 0, 0, 0);
                sc[rt][nt] = __builtin_amdgcn_mfma_f32_16x16x32_bf16(qf[rt][1], kc[nt][1], z, 0, 0, 0);
            }
#pragma unroll
        for (int rt = 0; rt < 2; ++rt)
#pragma unroll
            for (int nt = 0; nt < 4; ++nt)
#pragma unroll
                for (int r = 0; r < 4; ++r)
                    sc[rt][nt][r] = __expf(sc[rt][nt][r]);
        if (!fullband) {
#pragma unroll
            for (int rt = 0; rt < 2; ++rt)
#pragma unroll
                for (int nt = 0; nt < 4; ++nt) {
                    int kk = k0 + nt * 16 + lc;
#pragma unroll
                    for (int r = 0; r < 4; ++r) {
                        int dq = (qbase + rt * 16 + lg * 4 + r) - kk;
                        if (dq > WIN || dq < -WIN) sc[rt][nt][r] = 0.0f;
                    }
                }
        }
#pragma unroll
        for (int rt = 0; rt < 2; ++rt)
#pragma unroll
            for (int r = 0; r < 4; ++r)
                lsum[rt][r] += (sc[rt][0][r] + sc[rt][1][r]) + (sc[rt][2][r] + sc[rt][3][r]);
#pragma unroll
        for (int rt = 0; rt < 2; ++rt)
#pragma unroll
            for (int nt = 0; nt < 4; ++nt)
#pragma unroll
                for (int r = 0; r < 4; ++r)
                    Ps[wv][rt][lg * 4 + r][nt * 16 + lc] = f2bf(sc[rt][nt][r]);
#pragma unroll
        for (int rt = 0; rt < 2; ++rt) {
            short8 pa0 = *(const short8*)(&Ps[wv][rt][lc][lg * 8]);
            short8 pa1 = *(const short8*)(&Ps[wv][rt][lc][32 + lg * 8]);
#pragma unroll
            for (int nt2 = 0; nt2 < 4; ++nt2) {
                o[rt][nt2] = __builtin_amdgcn_mfma_f32_16x16x32_bf16(pa0, vf[nt2][0], o[rt][nt2], 0, 0, 0);
                o[rt][nt2] = __builtin_amdgcn_mfma_f32_16x16x32_bf16(pa1, vf[nt2][1], o[rt][nt2], 0, 0, 0);
            }
        }
    }

#pragma unroll
    for (int rt = 0; rt < 2; ++rt)
#pragma unroll
        for (int r = 0; r < 4; ++r) {
            float rs = lsum[rt][r];
#pragma unroll
            for (int off = 1; off < 16; off <<= 1)
                rs += __shfl_xor(rs, off, 64);
            lsum[rt][r] = 1.0f / rs;
        }
#pragma unroll
    for (int rt = 0; rt < 2; ++rt)
#pragma unroll
        for (int nt2 = 0; nt2 < 4; ++nt2)
#pragma unroll
            for (int r = 0; r < 4; ++r) {
                int q = qbase + rt * 16 + lg * 4 + r;
                int d = nt2 * 16 + lc;
                outp[((size_t)b * SS + q) * EE + h * HD + d] = o[rt][nt2][r] * lsum[rt][r];
            }
}

extern "C" void kernel_launch(void* const* d_in, const int* in_sizes, int n_in,
                              void* d_out, int out_size, void* d_ws, size_t ws_size,
                              hipStream_t stream) {
    const float* X  = (const float*)d_in[0];
    const float* Wq = (const float*)d_in[1];
    const float* bq = (const float*)d_in[2];
    const float* Wk = (const float*)d_in[3];
    const float* bk = (const float*)d_in[4];
    const float* Wv = (const float*)d_in[5];
    const float* bv = (const float*)d_in[6];

    const size_t qkv_elems = (size_t)BB * NH * SS * HD;   // 8,388,608 bf16 each
    unsigned short* Qw = (unsigned short*)d_ws;
    unsigned short* Kw = Qw + qkv_elems;
    unsigned short* Vw = Kw + qkv_elems;

    unsigned short* cvt = (unsigned short*)d_out;
    const unsigned short* Xb = cvt;
    const unsigned short* WbAll = cvt + 8388608;

    cvt_kernel<<<dim3(11264), 256, 0, stream>>>(X, Wq, Wk, Wv, cvt);
    qkv_gemm4<<<dim3(768), 512, 0, stream>>>(
        Xb, WbAll, bq, bk, bv, Qw, Kw, Vw);
    swa_kernel<<<dim3(NH, SS / 128, BB), 256, 0, stream>>>(Qw, Kw, Vw, (float*)d_out);
}

// Round 4
// 197.594 us; speedup vs baseline: 2.1785x; 2.1785x over previous
//
#include <hip/hip_runtime.h>

#define NH 16
#define HD 64
#define WIN 256
#define BB 2
#define SS 4096
#define EE 1024

typedef __attribute__((ext_vector_type(8))) short short8;
typedef __attribute__((ext_vector_type(4))) float floatx4;
typedef __attribute__((ext_vector_type(4))) unsigned short ushort4v;

__device__ inline unsigned short f2bf(float f) {
    unsigned u = __builtin_bit_cast(unsigned, f);
    u += 0x7fffu + ((u >> 16) & 1u);
    return (unsigned short)(u >> 16);
}

// ---------------- pass 0: f32 -> bf16 convert of X and W's into d_out scratch
__global__ __launch_bounds__(256)
void cvt_kernel(const float* __restrict__ X,
                const float* __restrict__ W0,
                const float* __restrict__ W1,
                const float* __restrict__ W2,
                unsigned short* __restrict__ out)
{
    size_t idx = (size_t)blockIdx.x * 256 + threadIdx.x;   // float4 index
    const size_t X4 = 2097152, W4 = 262144;                // float4 counts
    const float* src; unsigned short* dst; size_t off;
    if (idx < X4)                { src = X;  dst = out;            off = idx; }
    else if (idx < X4 + W4)      { src = W0; dst = out + 8388608;  off = idx - X4; }
    else if (idx < X4 + 2 * W4)  { src = W1; dst = out + 9437184;  off = idx - X4 - W4; }
    else                         { src = W2; dst = out + 10485760; off = idx - X4 - 2 * W4; }
    float4 v = ((const float4*)src)[off];
    ushort4 u;
    u.x = f2bf(v.x); u.y = f2bf(v.y); u.z = f2bf(v.z); u.w = f2bf(v.w);
    ((ushort4*)dst)[off] = u;
}

// ---------------- pass 1: bf16 GEMM, 128x128 tile, BK=32, 17.4 KB LDS.
// Identical per-wave structure to the proven 63.5us kernel (acc[4][4],
// 16x16x32 MFMA, global_load_lds staging, LDS-transpose epilogue). BK halved
// 64->32 so the LDS block drops 32->17.4 KB: residency rises 5 -> 8 blocks/CU,
// making all 1536 blocks co-resident (one dispatch round, no tail).
// VGPR stays ~64 (launch_bounds min-waves left at 4 => allocator cap 128).
__global__ __launch_bounds__(256, 4)
void qkv_gemm4(const unsigned short* __restrict__ Xb,
               const unsigned short* __restrict__ WbAll,
               const float* __restrict__ b0,
               const float* __restrict__ b1,
               const float* __restrict__ b2,
               unsigned short* __restrict__ Qo,
               unsigned short* __restrict__ Ko,
               unsigned short* __restrict__ Vo)
{
    const int id = blockIdx.x;           // 0..1535
    const int xcd = id & 7;
    const int rest = id >> 3;            // 0..191
    const int ytile = xcd + 8 * (rest & 7);   // 0..63, ytile%8 == xcd
    const int nm = rest >> 3;            // 0..23
    const int ntile = nm & 7;            // 0..7
    const int mode = nm >> 3;            // 0..2

    const unsigned short* Wm = WbAll + (size_t)mode * 1048576;
    const float* bm = (mode == 0) ? b0 : (mode == 1) ? b1 : b2;
    unsigned short* outp = (mode == 0) ? Qo : (mode == 1) ? Ko : Vo;

    const int m0 = ytile * 128;
    const int n0 = ntile * 128;
    const int t = threadIdx.x;
    const int lane = t & 63;
    const int wv = t >> 6;
    const int wm = wv >> 1, wn = wv & 1;
    const int lg = lane >> 4, lc = lane & 15;

    // 8704 ushorts = 17408 B: staging uses [0,8192), epilogue uses [0,8704)
    __shared__ __attribute__((aligned(16))) unsigned short smem[8704];
    unsigned short* As = smem;           // 128 x 32
    unsigned short* Bs = smem + 4096;    // 128 x 32

    const int srow = lane >> 2;          // 0..15
    const int scol = (lane & 3) * 8;     // 0,8,16,24

    floatx4 acc[4][4];
#pragma unroll
    for (int i = 0; i < 4; ++i)
#pragma unroll
        for (int j = 0; j < 4; ++j)
            acc[i][j] = (floatx4)0.0f;

    for (int kt = 0; kt < EE; kt += 32) {
        if (kt) __syncthreads();
#pragma unroll
        for (int seg = 0; seg < 2; ++seg) {
            int r0 = wv * 32 + seg * 16;     // 0..112, +srow covers 128 rows
            const unsigned short* asrc =
                Xb + (size_t)(m0 + r0 + srow) * EE + kt + scol;
            const unsigned short* bsrc =
                Wm + (size_t)(n0 + r0 + srow) * EE + kt + scol;
            __builtin_amdgcn_global_load_lds(
                (const __attribute__((address_space(1))) unsigned int*)asrc,
                (__attribute__((address_space(3))) unsigned int*)&As[r0 * 32], 16, 0, 0);
            __builtin_amdgcn_global_load_lds(
                (const __attribute__((address_space(1))) unsigned int*)bsrc,
                (__attribute__((address_space(3))) unsigned int*)&Bs[r0 * 32], 16, 0, 0);
        }
        __syncthreads();

        short8 af[4], bfr[4];
#pragma unroll
        for (int mt = 0; mt < 4; ++mt)
            af[mt] = *(const short8*)(&As[(wm * 64 + mt * 16 + lc) * 32 + lg * 8]);
#pragma unroll
        for (int nt = 0; nt < 4; ++nt)
            bfr[nt] = *(const short8*)(&Bs[(wn * 64 + nt * 16 + lc) * 32 + lg * 8]);
#pragma unroll
        for (int mt = 0; mt < 4; ++mt)
#pragma unroll
            for (int nt = 0; nt < 4; ++nt)
                acc[mt][nt] = __builtin_amdgcn_mfma_f32_16x16x32_bf16(
                    af[mt], bfr[nt], acc[mt][nt], 0, 0, 0);
    }

    const int CST = 136;
    const float qscale = (mode == 0) ? 0.125f : 1.0f;
#pragma unroll
    for (int p = 0; p < 2; ++p) {
        __syncthreads();
        if (mode < 2) {
            if (wm == p) {
#pragma unroll
                for (int nt = 0; nt < 4; ++nt) {
                    float bias = bm[n0 + wn * 64 + nt * 16 + lc];
#pragma unroll
                    for (int mt = 0; mt < 4; ++mt)
#pragma unroll
                        for (int r = 0; r < 4; ++r) {
                            int ml = mt * 16 + lg * 4 + r;
                            int nl = wn * 64 + nt * 16 + lc;
                            smem[ml * CST + nl] = f2bf((acc[mt][nt][r] + bias) * qscale);
                        }
                }
            }
        } else {
            if (wn == p) {
#pragma unroll
                for (int nt = 0; nt < 4; ++nt) {
                    float bias = bm[n0 + p * 64 + nt * 16 + lc];
#pragma unroll
                    for (int mt = 0; mt < 4; ++mt) {
                        ushort4v pk;
#pragma unroll
                        for (int r = 0; r < 4; ++r)
                            pk[r] = f2bf(acc[mt][nt][r] + bias);
                        int nl = nt * 16 + lc;
                        int col = wm * 64 + mt * 16 + lg * 4;
                        *(ushort4v*)(&smem[nl * CST + col]) = pk;
                    }
                }
            }
        }
        __syncthreads();
#pragma unroll
        for (int q = 0; q < 4; ++q) {
            int c = q * 256 + t;
            int row = c >> 4;
            int j = c & 15;
            uint4 val = *(const uint4*)(&smem[row * CST + j * 8]);
            if (mode < 2) {
                int m = m0 + p * 64 + row;
                int bb = m >> 12, s = m & (SS - 1);
                int n = n0 + j * 8;
                int hh = n >> 6, dd = n & 63;
                *(uint4*)(outp + (((size_t)bb * NH + hh) * SS + s) * HD + dd) = val;
            } else {
                int n = n0 + p * 64 + row;
                int hh = n >> 6, dd = n & 63;
                int m = m0 + j * 8;
                int bb = m >> 12, s = m & (SS - 1);
                *(uint4*)(outp + (((size_t)bb * NH + hh) * HD + dd) * SS + s) = val;
            }
        }
    }
}

// ---------------- pass 2: banded flash attention, unnormalized streaming softmax
// (round-0 proven version: QBLK=128, 4 waves)
__global__ __launch_bounds__(256, 2)
void swa_kernel(const unsigned short* __restrict__ Qp_,
                const unsigned short* __restrict__ Kp_,
                const unsigned short* __restrict__ Vp_,
                float* __restrict__ outp)
{
    const int h = blockIdx.x;
    const int q0 = blockIdx.y * 128;
    const int b = blockIdx.z;
    const int t = threadIdx.x, lane = t & 63, wv = t >> 6;
    const int lg = lane >> 4, lc = lane & 15;
    const size_t bh = (size_t)b * NH + h;
    const unsigned short* Qp = Qp_ + bh * (size_t)SS * HD;
    const unsigned short* Kp = Kp_ + bh * (size_t)SS * HD;
    const unsigned short* Vp = Vp_ + bh * (size_t)HD * SS;
    const int qbase = q0 + wv * 32;

    short8 qf[2][2];
#pragma unroll
    for (int rt = 0; rt < 2; ++rt)
#pragma unroll
        for (int hh = 0; hh < 2; ++hh)
            qf[rt][hh] = *(const short8*)(Qp + (size_t)(qbase + rt * 16 + lc) * HD + hh * 32 + lg * 8);

    floatx4 o[2][4];
    float lsum[2][4];
#pragma unroll
    for (int rt = 0; rt < 2; ++rt)
#pragma unroll
        for (int i = 0; i < 4; ++i) { o[rt][i] = (floatx4)0.0f; lsum[rt][i] = 0.0f; }

    __shared__ __attribute__((aligned(16))) unsigned short kvs[2][2][4096];
    __shared__ __attribute__((aligned(16))) unsigned short Ps[4][2][16][72];

    const int kbeg = (q0 >= WIN) ? (q0 - WIN) : 0;
    const int kend = (q0 + 128 + WIN <= SS) ? (q0 + 128 + WIN) : SS;

    const int sr = lane >> 3;
    const int sj = lane & 7;
    const int swz = (sj ^ sr) * 8;

#define STAGE(buf, k0_)                                                              \
    {                                                                                \
        _Pragma("unroll")                                                            \
        for (int i = 0; i < 2; ++i) {                                                \
            int rbase = 16 * wv + i * 8;                                             \
            const unsigned short* ks = Kp + (size_t)((k0_) + rbase + sr) * HD + swz; \
            const unsigned short* vs = Vp + (size_t)(rbase + sr) * SS + (k0_) + swz; \
            __builtin_amdgcn_global_load_lds(                                        \
                (const __attribute__((address_space(1))) unsigned int*)ks,           \
                (__attribute__((address_space(3))) unsigned int*)&kvs[buf][0][rbase * 64], 16, 0, 0); \
            __builtin_amdgcn_global_load_lds(                                        \
                (const __attribute__((address_space(1))) unsigned int*)vs,           \
                (__attribute__((address_space(3))) unsigned int*)&kvs[buf][1][rbase * 64], 16, 0, 0); \
        }                                                                            \
    }

    STAGE(0, kbeg)

    int cur = 0;
    for (int k0 = kbeg; k0 < kend; k0 += 64, cur ^= 1) {
        __syncthreads();
        bool active = (k0 + 63 >= qbase - WIN) && (k0 <= qbase + 31 + WIN);
        short8 kc[4][2], vf[4][2];
        if (active) {
#pragma unroll
            for (int nt = 0; nt < 4; ++nt)
#pragma unroll
                for (int hh = 0; hh < 2; ++hh) {
                    int row = nt * 16 + lc;
                    kc[nt][hh] = *(const short8*)(&kvs[cur][0][row * 64 + (((hh * 4 + lg) ^ (row & 7)) * 8)]);
                    vf[nt][hh] = *(const short8*)(&kvs[cur][1][row * 64 + (((hh * 4 + lg) ^ (row & 7)) * 8)]);
                }
        }
        if (k0 + 64 < kend) STAGE(cur ^ 1, k0 + 64)
        if (!active) continue;

        bool fullband = (k0 >= qbase - 225) && (k0 <= qbase + 193);

        floatx4 sc[2][4];
#pragma unroll
        for (int rt = 0; rt < 2; ++rt)
#pragma unroll
            for (int nt = 0; nt < 4; ++nt) {
                floatx4 z = (floatx4)0.0f;
                z = __builtin_amdgcn_mfma_f32_16x16x32_bf16(qf[rt][0], kc[nt][0], z, 0, 0, 0);
                sc[rt][nt] = __builtin_amdgcn_mfma_f32_16x16x32_bf16(qf[rt][1], kc[nt][1], z, 0, 0, 0);
            }
#pragma unroll
        for (int rt = 0; rt < 2; ++rt)
#pragma unroll
            for (int nt = 0; nt < 4; ++nt)
#pragma unroll
                for (int r = 0; r < 4; ++r)
                    sc[rt][nt][r] = __expf(sc[rt][nt][r]);
        if (!fullband) {
#pragma unroll
            for (int rt = 0; rt < 2; ++rt)
#pragma unroll
                for (int nt = 0; nt < 4; ++nt) {
                    int kk = k0 + nt * 16 + lc;
#pragma unroll
                    for (int r = 0; r < 4; ++r) {
                        int dq = (qbase + rt * 16 + lg * 4 + r) - kk;
                        if (dq > WIN || dq < -WIN) sc[rt][nt][r] = 0.0f;
                    }
                }
        }
#pragma unroll
        for (int rt = 0; rt < 2; ++rt)
#pragma unroll
            for (int r = 0; r < 4; ++r)
                lsum[rt][r] += (sc[rt][0][r] + sc[rt][1][r]) + (sc[rt][2][r] + sc[rt][3][r]);
#pragma unroll
        for (int rt = 0; rt < 2; ++rt)
#pragma unroll
            for (int nt = 0; nt < 4; ++nt)
#pragma unroll
                for (int r = 0; r < 4; ++r)
                    Ps[wv][rt][lg * 4 + r][nt * 16 + lc] = f2bf(sc[rt][nt][r]);
#pragma unroll
        for (int rt = 0; rt < 2; ++rt) {
            short8 pa0 = *(const short8*)(&Ps[wv][rt][lc][lg * 8]);
            short8 pa1 = *(const short8*)(&Ps[wv][rt][lc][32 + lg * 8]);
#pragma unroll
            for (int nt2 = 0; nt2 < 4; ++nt2) {
                o[rt][nt2] = __builtin_amdgcn_mfma_f32_16x16x32_bf16(pa0, vf[nt2][0], o[rt][nt2], 0, 0, 0);
                o[rt][nt2] = __builtin_amdgcn_mfma_f32_16x16x32_bf16(pa1, vf[nt2][1], o[rt][nt2], 0, 0, 0);
            }
        }
    }

#pragma unroll
    for (int rt = 0; rt < 2; ++rt)
#pragma unroll
        for (int r = 0; r < 4; ++r) {
            float rs = lsum[rt][r];
#pragma unroll
            for (int off = 1; off < 16; off <<= 1)
                rs += __shfl_xor(rs, off, 64);
            lsum[rt][r] = 1.0f / rs;
        }
#pragma unroll
    for (int rt = 0; rt < 2; ++rt)
#pragma unroll
        for (int nt2 = 0; nt2 < 4; ++nt2)
#pragma unroll
            for (int r = 0; r < 4; ++r) {
                int q = qbase + rt * 16 + lg * 4 + r;
                int d = nt2 * 16 + lc;
                outp[((size_t)b * SS + q) * EE + h * HD + d] = o[rt][nt2][r] * lsum[rt][r];
            }
}

extern "C" void kernel_launch(void* const* d_in, const int* in_sizes, int n_in,
                              void* d_out, int out_size, void* d_ws, size_t ws_size,
                              hipStream_t stream) {
    const float* X  = (const float*)d_in[0];
    const float* Wq = (const float*)d_in[1];
    const float* bq = (const float*)d_in[2];
    const float* Wk = (const float*)d_in[3];
    const float* bk = (const float*)d_in[4];
    const float* Wv = (const float*)d_in[5];
    const float* bv = (const float*)d_in[6];

    const size_t qkv_elems = (size_t)BB * NH * SS * HD;   // 8,388,608 bf16 each
    unsigned short* Qw = (unsigned short*)d_ws;
    unsigned short* Kw = Qw + qkv_elems;
    unsigned short* Vw = Kw + qkv_elems;

    unsigned short* cvt = (unsigned short*)d_out;
    const unsigned short* Xb = cvt;
    const unsigned short* WbAll = cvt + 8388608;

    cvt_kernel<<<dim3(11264), 256, 0, stream>>>(X, Wq, Wk, Wv, cvt);
    qkv_gemm4<<<dim3(1536), 256, 0, stream>>>(
        Xb, WbAll, bq, bk, bv, Qw, Kw, Vw);
    swa_kernel<<<dim3(NH, SS / 128, BB), 256, 0, stream>>>(Qw, Kw, Vw, (float*)d_out);
}

// Round 5
// 193.518 us; speedup vs baseline: 2.2244x; 1.0211x over previous
//
#include <hip/hip_runtime.h>

#define NH 16
#define HD 64
#define WIN 256
#define BB 2
#define SS 4096
#define EE 1024

typedef __attribute__((ext_vector_type(8))) short short8;
typedef __attribute__((ext_vector_type(4))) float floatx4;
typedef __attribute__((ext_vector_type(4))) unsigned short ushort4v;

__device__ inline unsigned short f2bf(float f) {
    unsigned u = __builtin_bit_cast(unsigned, f);
    u += 0x7fffu + ((u >> 16) & 1u);
    return (unsigned short)(u >> 16);
}

// ---------------- pass 0: f32 -> bf16 convert of X and W's into d_out scratch
__global__ __launch_bounds__(256)
void cvt_kernel(const float* __restrict__ X,
                const float* __restrict__ W0,
                const float* __restrict__ W1,
                const float* __restrict__ W2,
                unsigned short* __restrict__ out)
{
    size_t idx = (size_t)blockIdx.x * 256 + threadIdx.x;   // float4 index
    const size_t X4 = 2097152, W4 = 262144;                // float4 counts
    const float* src; unsigned short* dst; size_t off;
    if (idx < X4)                { src = X;  dst = out;            off = idx; }
    else if (idx < X4 + W4)      { src = W0; dst = out + 8388608;  off = idx - X4; }
    else if (idx < X4 + 2 * W4)  { src = W1; dst = out + 9437184;  off = idx - X4 - W4; }
    else                         { src = W2; dst = out + 10485760; off = idx - X4 - 2 * W4; }
    float4 v = ((const float4*)src)[off];
    ushort4 u;
    u.x = f2bf(v.x); u.y = f2bf(v.y); u.z = f2bf(v.z); u.w = f2bf(v.w);
    ((ushort4*)dst)[off] = u;
}

// ---------------- pass 1: bf16 GEMM, BK=64, LDS-transposed coalesced epilogue.
// Proven round-0 configuration (63.5us, 813 TF): 128x128 tile, 4 waves,
// 2-barrier K-loop, global_load_lds staging. DO NOT restructure: 256^2/8-phase
// (89us), BM=256/8-wave (VGPR spill, 300us) and BK=32 (76us) all regressed.
__global__ __launch_bounds__(256, 4)
void qkv_gemm4(const unsigned short* __restrict__ Xb,
               const unsigned short* __restrict__ WbAll,
               const float* __restrict__ b0,
               const float* __restrict__ b1,
               const float* __restrict__ b2,
               unsigned short* __restrict__ Qo,
               unsigned short* __restrict__ Ko,
               unsigned short* __restrict__ Vo)
{
    const int id = blockIdx.x;           // 0..1535
    const int xcd = id & 7;
    const int rest = id >> 3;            // 0..191
    const int ytile = xcd + 8 * (rest & 7);   // 0..63, ytile%8 == xcd
    const int nm = rest >> 3;            // 0..23
    const int ntile = nm & 7;            // 0..7
    const int mode = nm >> 3;            // 0..2

    const unsigned short* Wm = WbAll + (size_t)mode * 1048576;
    const float* bm = (mode == 0) ? b0 : (mode == 1) ? b1 : b2;
    unsigned short* outp = (mode == 0) ? Qo : (mode == 1) ? Ko : Vo;

    const int m0 = ytile * 128;
    const int n0 = ntile * 128;
    const int t = threadIdx.x;
    const int lane = t & 63;
    const int wv = t >> 6;
    const int wm = wv >> 1, wn = wv & 1;
    const int lg = lane >> 4, lc = lane & 15;

    __shared__ __attribute__((aligned(16))) unsigned short smem[16384];
    unsigned short* As[2] = { smem, smem + 4096 };
    unsigned short* Bs[2] = { smem + 8192, smem + 12288 };

    const int srow = lane >> 2;
    const int scol = (lane & 3) * 8;

    floatx4 acc[4][4];
#pragma unroll
    for (int i = 0; i < 4; ++i)
#pragma unroll
        for (int j = 0; j < 4; ++j)
            acc[i][j] = (floatx4)0.0f;

    for (int kt = 0; kt < EE; kt += 64) {
        if (kt) __syncthreads();
#pragma unroll
        for (int half = 0; half < 2; ++half) {
#pragma unroll
            for (int seg = 0; seg < 2; ++seg) {
                int r0 = wv * 32 + seg * 16;
                const unsigned short* asrc =
                    Xb + (size_t)(m0 + r0 + srow) * EE + kt + half * 32 + scol;
                const unsigned short* bsrc =
                    Wm + (size_t)(n0 + r0 + srow) * EE + kt + half * 32 + scol;
                __builtin_amdgcn_global_load_lds(
                    (const __attribute__((address_space(1))) unsigned int*)asrc,
                    (__attribute__((address_space(3))) unsigned int*)&As[half][r0 * 32], 16, 0, 0);
                __builtin_amdgcn_global_load_lds(
                    (const __attribute__((address_space(1))) unsigned int*)bsrc,
                    (__attribute__((address_space(3))) unsigned int*)&Bs[half][r0 * 32], 16, 0, 0);
            }
        }
        __syncthreads();

#pragma unroll
        for (int half = 0; half < 2; ++half) {
            short8 af[4], bfr[4];
#pragma unroll
            for (int mt = 0; mt < 4; ++mt)
                af[mt] = *(const short8*)(&As[half][(wm * 64 + mt * 16 + lc) * 32 + lg * 8]);
#pragma unroll
            for (int nt = 0; nt < 4; ++nt)
                bfr[nt] = *(const short8*)(&Bs[half][(wn * 64 + nt * 16 + lc) * 32 + lg * 8]);
#pragma unroll
            for (int mt = 0; mt < 4; ++mt)
#pragma unroll
                for (int nt = 0; nt < 4; ++nt)
                    acc[mt][nt] = __builtin_amdgcn_mfma_f32_16x16x32_bf16(
                        af[mt], bfr[nt], acc[mt][nt], 0, 0, 0);
        }
    }

    const int CST = 136;
    const float qscale = (mode == 0) ? 0.125f : 1.0f;
#pragma unroll
    for (int p = 0; p < 2; ++p) {
        __syncthreads();
        if (mode < 2) {
            if (wm == p) {
#pragma unroll
                for (int nt = 0; nt < 4; ++nt) {
                    float bias = bm[n0 + wn * 64 + nt * 16 + lc];
#pragma unroll
                    for (int mt = 0; mt < 4; ++mt)
#pragma unroll
                        for (int r = 0; r < 4; ++r) {
                            int ml = mt * 16 + lg * 4 + r;
                            int nl = wn * 64 + nt * 16 + lc;
                            smem[ml * CST + nl] = f2bf((acc[mt][nt][r] + bias) * qscale);
                        }
                }
            }
        } else {
            if (wn == p) {
#pragma unroll
                for (int nt = 0; nt < 4; ++nt) {
                    float bias = bm[n0 + p * 64 + nt * 16 + lc];
#pragma unroll
                    for (int mt = 0; mt < 4; ++mt) {
                        ushort4v pk;
#pragma unroll
                        for (int r = 0; r < 4; ++r)
                            pk[r] = f2bf(acc[mt][nt][r] + bias);
                        int nl = nt * 16 + lc;
                        int col = wm * 64 + mt * 16 + lg * 4;
                        *(ushort4v*)(&smem[nl * CST + col]) = pk;
                    }
                }
            }
        }
        __syncthreads();
#pragma unroll
        for (int q = 0; q < 4; ++q) {
            int c = q * 256 + t;
            int row = c >> 4;
            int j = c & 15;
            uint4 val = *(const uint4*)(&smem[row * CST + j * 8]);
            if (mode < 2) {
                int m = m0 + p * 64 + row;
                int bb = m >> 12, s = m & (SS - 1);
                int n = n0 + j * 8;
                int hh = n >> 6, dd = n & 63;
                *(uint4*)(outp + (((size_t)bb * NH + hh) * SS + s) * HD + dd) = val;
            } else {
                int n = n0 + p * 64 + row;
                int hh = n >> 6, dd = n & 63;
                int m = m0 + j * 8;
                int bb = m >> 12, s = m & (SS - 1);
                *(uint4*)(outp + (((size_t)bb * NH + hh) * HD + dd) * SS + s) = val;
            }
        }
    }
}

// ---------------- pass 2: banded flash attention, unnormalized streaming softmax
// Round-0 proven structure (QBLK=128, 4 waves). ONE change: 1-D grid with
// XCD-locality remap. Old grid made h the fastest block index -> consecutive
// blocks used different heads' K/V (zero L2 reuse; 5x re-fetch served from L3).
// New mapping pins all 32 q-blocks of a (b,h) to one XCD (id&7) and gives each
// XCD 4 (b,h) groups: K+V per group = 1MB, 4 groups = 4MB = one XCD L2.
__global__ __launch_bounds__(256, 2)
void swa_kernel(const unsigned short* __restrict__ Qp_,
                const unsigned short* __restrict__ Kp_,
                const unsigned short* __restrict__ Vp_,
                float* __restrict__ outp)
{
    const int id = blockIdx.x;            // 0..1023
    const int xcd = id & 7;
    const int idx = id >> 3;              // 0..127
    const int bh = xcd + 8 * (idx >> 5);  // 0..31, bh%8 == xcd
    const int q0 = (idx & 31) * 128;
    const int b = bh >> 4;
    const int h = bh & 15;
    const int t = threadIdx.x, lane = t & 63, wv = t >> 6;
    const int lg = lane >> 4, lc = lane & 15;
    const size_t bhs = (size_t)b * NH + h;
    const unsigned short* Qp = Qp_ + bhs * (size_t)SS * HD;
    const unsigned short* Kp = Kp_ + bhs * (size_t)SS * HD;
    const unsigned short* Vp = Vp_ + bhs * (size_t)HD * SS;
    const int qbase = q0 + wv * 32;

    short8 qf[2][2];
#pragma unroll
    for (int rt = 0; rt < 2; ++rt)
#pragma unroll
        for (int hh = 0; hh < 2; ++hh)
            qf[rt][hh] = *(const short8*)(Qp + (size_t)(qbase + rt * 16 + lc) * HD + hh * 32 + lg * 8);

    floatx4 o[2][4];
    float lsum[2][4];
#pragma unroll
    for (int rt = 0; rt < 2; ++rt)
#pragma unroll
        for (int i = 0; i < 4; ++i) { o[rt][i] = (floatx4)0.0f; lsum[rt][i] = 0.0f; }

    __shared__ __attribute__((aligned(16))) unsigned short kvs[2][2][4096];
    __shared__ __attribute__((aligned(16))) unsigned short Ps[4][2][16][72];

    const int kbeg = (q0 >= WIN) ? (q0 - WIN) : 0;
    const int kend = (q0 + 128 + WIN <= SS) ? (q0 + 128 + WIN) : SS;

    const int sr = lane >> 3;
    const int sj = lane & 7;
    const int swz = (sj ^ sr) * 8;

#define STAGE(buf, k0_)                                                              \
    {                                                                                \
        _Pragma("unroll")                                                            \
        for (int i = 0; i < 2; ++i) {                                                \
            int rbase = 16 * wv + i * 8;                                             \
            const unsigned short* ks = Kp + (size_t)((k0_) + rbase + sr) * HD + swz; \
            const unsigned short* vs = Vp + (size_t)(rbase + sr) * SS + (k0_) + swz; \
            __builtin_amdgcn_global_load_lds(                                        \
                (const __attribute__((address_space(1))) unsigned int*)ks,           \
                (__attribute__((address_space(3))) unsigned int*)&kvs[buf][0][rbase * 64], 16, 0, 0); \
            __builtin_amdgcn_global_load_lds(                                        \
                (const __attribute__((address_space(1))) unsigned int*)vs,           \
                (__attribute__((address_space(3))) unsigned int*)&kvs[buf][1][rbase * 64], 16, 0, 0); \
        }                                                                            \
    }

    STAGE(0, kbeg)

    int cur = 0;
    for (int k0 = kbeg; k0 < kend; k0 += 64, cur ^= 1) {
        __syncthreads();
        bool active = (k0 + 63 >= qbase - WIN) && (k0 <= qbase + 31 + WIN);
        short8 kc[4][2], vf[4][2];
        if (active) {
#pragma unroll
            for (int nt = 0; nt < 4; ++nt)
#pragma unroll
                for (int hh = 0; hh < 2; ++hh) {
                    int row = nt * 16 + lc;
                    kc[nt][hh] = *(const short8*)(&kvs[cur][0][row * 64 + (((hh * 4 + lg) ^ (row & 7)) * 8)]);
                    vf[nt][hh] = *(const short8*)(&kvs[cur][1][row * 64 + (((hh * 4 + lg) ^ (row & 7)) * 8)]);
                }
        }
        if (k0 + 64 < kend) STAGE(cur ^ 1, k0 + 64)
        if (!active) continue;

        bool fullband = (k0 >= qbase - 225) && (k0 <= qbase + 193);

        floatx4 sc[2][4];
#pragma unroll
        for (int rt = 0; rt < 2; ++rt)
#pragma unroll
            for (int nt = 0; nt < 4; ++nt) {
                floatx4 z = (floatx4)0.0f;
                z = __builtin_amdgcn_mfma_f32_16x16x32_bf16(qf[rt][0], kc[nt][0], z, 0, 0, 0);
                sc[rt][nt] = __builtin_amdgcn_mfma_f32_16x16x32_bf16(qf[rt][1], kc[nt][1], z, 0, 0, 0);
            }
#pragma unroll
        for (int rt = 0; rt < 2; ++rt)
#pragma unroll
            for (int nt = 0; nt < 4; ++nt)
#pragma unroll
                for (int r = 0; r < 4; ++r)
                    sc[rt][nt][r] = __expf(sc[rt][nt][r]);
        if (!fullband) {
#pragma unroll
            for (int rt = 0; rt < 2; ++rt)
#pragma unroll
                for (int nt = 0; nt < 4; ++nt) {
                    int kk = k0 + nt * 16 + lc;
#pragma unroll
                    for (int r = 0; r < 4; ++r) {
                        int dq = (qbase + rt * 16 + lg * 4 + r) - kk;
                        if (dq > WIN || dq < -WIN) sc[rt][nt][r] = 0.0f;
                    }
                }
        }
#pragma unroll
        for (int rt = 0; rt < 2; ++rt)
#pragma unroll
            for (int r = 0; r < 4; ++r)
                lsum[rt][r] += (sc[rt][0][r] + sc[rt][1][r]) + (sc[rt][2][r] + sc[rt][3][r]);
#pragma unroll
        for (int rt = 0; rt < 2; ++rt)
#pragma unroll
            for (int nt = 0; nt < 4; ++nt)
#pragma unroll
                for (int r = 0; r < 4; ++r)
                    Ps[wv][rt][lg * 4 + r][nt * 16 + lc] = f2bf(sc[rt][nt][r]);
#pragma unroll
        for (int rt = 0; rt < 2; ++rt) {
            short8 pa0 = *(const short8*)(&Ps[wv][rt][lc][lg * 8]);
            short8 pa1 = *(const short8*)(&Ps[wv][rt][lc][32 + lg * 8]);
#pragma unroll
            for (int nt2 = 0; nt2 < 4; ++nt2) {
                o[rt][nt2] = __builtin_amdgcn_mfma_f32_16x16x32_bf16(pa0, vf[nt2][0], o[rt][nt2], 0, 0, 0);
                o[rt][nt2] = __builtin_amdgcn_mfma_f32_16x16x32_bf16(pa1, vf[nt2][1], o[rt][nt2], 0, 0, 0);
            }
        }
    }

#pragma unroll
    for (int rt = 0; rt < 2; ++rt)
#pragma unroll
        for (int r = 0; r < 4; ++r) {
            float rs = lsum[rt][r];
#pragma unroll
            for (int off = 1; off < 16; off <<= 1)
                rs += __shfl_xor(rs, off, 64);
            lsum[rt][r] = 1.0f / rs;
        }
#pragma unroll
    for (int rt = 0; rt < 2; ++rt)
#pragma unroll
        for (int nt2 = 0; nt2 < 4; ++nt2)
#pragma unroll
            for (int r = 0; r < 4; ++r) {
                int q = qbase + rt * 16 + lg * 4 + r;
                int d = nt2 * 16 + lc;
                outp[((size_t)b * SS + q) * EE + h * HD + d] = o[rt][nt2][r] * lsum[rt][r];
            }
}

extern "C" void kernel_launch(void* const* d_in, const int* in_sizes, int n_in,
                              void* d_out, int out_size, void* d_ws, size_t ws_size,
                              hipStream_t stream) {
    const float* X  = (const float*)d_in[0];
    const float* Wq = (const float*)d_in[1];
    const float* bq = (const float*)d_in[2];
    const float* Wk = (const float*)d_in[3];
    const float* bk = (const float*)d_in[4];
    const float* Wv = (const float*)d_in[5];
    const float* bv = (const float*)d_in[6];

    const size_t qkv_elems = (size_t)BB * NH * SS * HD;   // 8,388,608 bf16 each
    unsigned short* Qw = (unsigned short*)d_ws;
    unsigned short* Kw = Qw + qkv_elems;
    unsigned short* Vw = Kw + qkv_elems;

    unsigned short* cvt = (unsigned short*)d_out;
    const unsigned short* Xb = cvt;
    const unsigned short* WbAll = cvt + 8388608;

    cvt_kernel<<<dim3(11264), 256, 0, stream>>>(X, Wq, Wk, Wv, cvt);
    qkv_gemm4<<<dim3(1536), 256, 0, stream>>>(
        Xb, WbAll, bq, bk, bv, Qw, Kw, Vw);
    swa_kernel<<<dim3(1024), 256, 0, stream>>>(Qw, Kw, Vw, (float*)d_out);
}

// Round 6
// 192.451 us; speedup vs baseline: 2.2367x; 1.0055x over previous
//
#include <hip/hip_runtime.h>

#define NH 16
#define HD 64
#define WIN 256
#define BB 2
#define SS 4096
#define EE 1024

typedef __attribute__((ext_vector_type(8))) short short8;
typedef __attribute__((ext_vector_type(4))) float floatx4;
typedef __attribute__((ext_vector_type(4))) unsigned short ushort4v;

__device__ inline unsigned short f2bf(float f) {
    unsigned u = __builtin_bit_cast(unsigned, f);
    u += 0x7fffu + ((u >> 16) & 1u);
    return (unsigned short)(u >> 16);
}

// ---------------- pass 0: f32 -> bf16 convert of X and W's into d_out scratch
__global__ __launch_bounds__(256)
void cvt_kernel(const float* __restrict__ X,
                const float* __restrict__ W0,
                const float* __restrict__ W1,
                const float* __restrict__ W2,
                unsigned short* __restrict__ out)
{
    size_t idx = (size_t)blockIdx.x * 256 + threadIdx.x;   // float4 index
    const size_t X4 = 2097152, W4 = 262144;                // float4 counts
    const float* src; unsigned short* dst; size_t off;
    if (idx < X4)                { src = X;  dst = out;            off = idx; }
    else if (idx < X4 + W4)      { src = W0; dst = out + 8388608;  off = idx - X4; }
    else if (idx < X4 + 2 * W4)  { src = W1; dst = out + 9437184;  off = idx - X4 - W4; }
    else                         { src = W2; dst = out + 10485760; off = idx - X4 - 2 * W4; }
    float4 v = ((const float4*)src)[off];
    ushort4 u;
    u.x = f2bf(v.x); u.y = f2bf(v.y); u.z = f2bf(v.z); u.w = f2bf(v.w);
    ((ushort4*)dst)[off] = u;
}

// ---------------- pass 1: bf16 GEMM, BK=64, LDS-transposed coalesced epilogue.
// Proven round-0 configuration (63.5us at full clock, 813 TF): 128x128 tile,
// 4 waves, 2-barrier K-loop, global_load_lds staging. DO NOT restructure:
// 256^2/8-phase (89us), BM=256/8-wave (VGPR spill, 300us), BK=32 (76us at
// full clock) all regressed.
__global__ __launch_bounds__(256, 4)
void qkv_gemm4(const unsigned short* __restrict__ Xb,
               const unsigned short* __restrict__ WbAll,
               const float* __restrict__ b0,
               const float* __restrict__ b1,
               const float* __restrict__ b2,
               unsigned short* __restrict__ Qo,
               unsigned short* __restrict__ Ko,
               unsigned short* __restrict__ Vo)
{
    const int id = blockIdx.x;           // 0..1535
    const int xcd = id & 7;
    const int rest = id >> 3;            // 0..191
    const int ytile = xcd + 8 * (rest & 7);   // 0..63, ytile%8 == xcd
    const int nm = rest >> 3;            // 0..23
    const int ntile = nm & 7;            // 0..7
    const int mode = nm >> 3;            // 0..2

    const unsigned short* Wm = WbAll + (size_t)mode * 1048576;
    const float* bm = (mode == 0) ? b0 : (mode == 1) ? b1 : b2;
    unsigned short* outp = (mode == 0) ? Qo : (mode == 1) ? Ko : Vo;

    const int m0 = ytile * 128;
    const int n0 = ntile * 128;
    const int t = threadIdx.x;
    const int lane = t & 63;
    const int wv = t >> 6;
    const int wm = wv >> 1, wn = wv & 1;
    const int lg = lane >> 4, lc = lane & 15;

    __shared__ __attribute__((aligned(16))) unsigned short smem[16384];
    unsigned short* As[2] = { smem, smem + 4096 };
    unsigned short* Bs[2] = { smem + 8192, smem + 12288 };

    const int srow = lane >> 2;
    const int scol = (lane & 3) * 8;

    floatx4 acc[4][4];
#pragma unroll
    for (int i = 0; i < 4; ++i)
#pragma unroll
        for (int j = 0; j < 4; ++j)
            acc[i][j] = (floatx4)0.0f;

    for (int kt = 0; kt < EE; kt += 64) {
        if (kt) __syncthreads();
#pragma unroll
        for (int half = 0; half < 2; ++half) {
#pragma unroll
            for (int seg = 0; seg < 2; ++seg) {
                int r0 = wv * 32 + seg * 16;
                const unsigned short* asrc =
                    Xb + (size_t)(m0 + r0 + srow) * EE + kt + half * 32 + scol;
                const unsigned short* bsrc =
                    Wm + (size_t)(n0 + r0 + srow) * EE + kt + half * 32 + scol;
                __builtin_amdgcn_global_load_lds(
                    (const __attribute__((address_space(1))) unsigned int*)asrc,
                    (__attribute__((address_space(3))) unsigned int*)&As[half][r0 * 32], 16, 0, 0);
                __builtin_amdgcn_global_load_lds(
                    (const __attribute__((address_space(1))) unsigned int*)bsrc,
                    (__attribute__((address_space(3))) unsigned int*)&Bs[half][r0 * 32], 16, 0, 0);
            }
        }
        __syncthreads();

#pragma unroll
        for (int half = 0; half < 2; ++half) {
            short8 af[4], bfr[4];
#pragma unroll
            for (int mt = 0; mt < 4; ++mt)
                af[mt] = *(const short8*)(&As[half][(wm * 64 + mt * 16 + lc) * 32 + lg * 8]);
#pragma unroll
            for (int nt = 0; nt < 4; ++nt)
                bfr[nt] = *(const short8*)(&Bs[half][(wn * 64 + nt * 16 + lc) * 32 + lg * 8]);
#pragma unroll
            for (int mt = 0; mt < 4; ++mt)
#pragma unroll
                for (int nt = 0; nt < 4; ++nt)
                    acc[mt][nt] = __builtin_amdgcn_mfma_f32_16x16x32_bf16(
                        af[mt], bfr[nt], acc[mt][nt], 0, 0, 0);
        }
    }

    const int CST = 136;
    const float qscale = (mode == 0) ? 0.125f : 1.0f;
#pragma unroll
    for (int p = 0; p < 2; ++p) {
        __syncthreads();
        if (mode < 2) {
            if (wm == p) {
#pragma unroll
                for (int nt = 0; nt < 4; ++nt) {
                    float bias = bm[n0 + wn * 64 + nt * 16 + lc];
#pragma unroll
                    for (int mt = 0; mt < 4; ++mt)
#pragma unroll
                        for (int r = 0; r < 4; ++r) {
                            int ml = mt * 16 + lg * 4 + r;
                            int nl = wn * 64 + nt * 16 + lc;
                            smem[ml * CST + nl] = f2bf((acc[mt][nt][r] + bias) * qscale);
                        }
                }
            }
        } else {
            if (wn == p) {
#pragma unroll
                for (int nt = 0; nt < 4; ++nt) {
                    float bias = bm[n0 + p * 64 + nt * 16 + lc];
#pragma unroll
                    for (int mt = 0; mt < 4; ++mt) {
                        ushort4v pk;
#pragma unroll
                        for (int r = 0; r < 4; ++r)
                            pk[r] = f2bf(acc[mt][nt][r] + bias);
                        int nl = nt * 16 + lc;
                        int col = wm * 64 + mt * 16 + lg * 4;
                        *(ushort4v*)(&smem[nl * CST + col]) = pk;
                    }
                }
            }
        }
        __syncthreads();
#pragma unroll
        for (int q = 0; q < 4; ++q) {
            int c = q * 256 + t;
            int row = c >> 4;
            int j = c & 15;
            uint4 val = *(const uint4*)(&smem[row * CST + j * 8]);
            if (mode < 2) {
                int m = m0 + p * 64 + row;
                int bb = m >> 12, s = m & (SS - 1);
                int n = n0 + j * 8;
                int hh = n >> 6, dd = n & 63;
                *(uint4*)(outp + (((size_t)bb * NH + hh) * SS + s) * HD + dd) = val;
            } else {
                int n = n0 + p * 64 + row;
                int hh = n >> 6, dd = n & 63;
                int m = m0 + j * 8;
                int bb = m >> 12, s = m & (SS - 1);
                *(uint4*)(outp + (((size_t)bb * NH + hh) * HD + dd) * SS + s) = val;
            }
        }
    }
}

// ---------------- pass 2: banded flash attention, unnormalized streaming softmax
// 8 waves x 16 q-rows (QBLK=128, 512 threads): per-wave VGPR halves
// (~170 -> ~110), launch_bounds(512,4) caps at 128 => 2 blocks/CU =
// 16 waves/CU, double the TLP of the 4-wave version. XCD-locality remap kept
// (R5: -4us). Per-tile math identical to proven version with the rt loop
// dropped; vf loaded per-nt2 after sc dies to keep peak pressure low.
__global__ __launch_bounds__(512, 4)
void swa_kernel(const unsigned short* __restrict__ Qp_,
                const unsigned short* __restrict__ Kp_,
                const unsigned short* __restrict__ Vp_,
                float* __restrict__ outp)
{
    const int id = blockIdx.x;            // 0..1023
    const int xcd = id & 7;
    const int idx = id >> 3;              // 0..127
    const int bh = xcd + 8 * (idx >> 5);  // 0..31, bh%8 == xcd
    const int q0 = (idx & 31) * 128;
    const int b = bh >> 4;
    const int h = bh & 15;
    const int t = threadIdx.x, lane = t & 63, wv = t >> 6;  // wv 0..7
    const int lg = lane >> 4, lc = lane & 15;
    const size_t bhs = (size_t)b * NH + h;
    const unsigned short* Qp = Qp_ + bhs * (size_t)SS * HD;
    const unsigned short* Kp = Kp_ + bhs * (size_t)SS * HD;
    const unsigned short* Vp = Vp_ + bhs * (size_t)HD * SS;
    const int qbase = q0 + wv * 16;       // 16 q-rows per wave

    short8 qf[2];
#pragma unroll
    for (int hh = 0; hh < 2; ++hh)
        qf[hh] = *(const short8*)(Qp + (size_t)(qbase + lc) * HD + hh * 32 + lg * 8);

    floatx4 o[4];
    float lsum[4];
#pragma unroll
    for (int i = 0; i < 4; ++i) { o[i] = (floatx4)0.0f; lsum[i] = 0.0f; }

    __shared__ __attribute__((aligned(16))) unsigned short kvs[2][2][4096];
    __shared__ __attribute__((aligned(16))) unsigned short Ps[8][16][72];

    const int kbeg = (q0 >= WIN) ? (q0 - WIN) : 0;
    const int kend = (q0 + 128 + WIN <= SS) ? (q0 + 128 + WIN) : SS;

    const int sr = lane >> 3;
    const int sj = lane & 7;
    const int swz = (sj ^ sr) * 8;

    // 8 waves x 8 rows = 64 rows per K-tile (K) and 64 d-rows (V)
#define STAGE(buf, k0_)                                                              \
    {                                                                                \
        const int rbase = 8 * wv;                                                    \
        const unsigned short* ks = Kp + (size_t)((k0_) + rbase + sr) * HD + swz;     \
        const unsigned short* vs = Vp + (size_t)(rbase + sr) * SS + (k0_) + swz;     \
        __builtin_amdgcn_global_load_lds(                                            \
            (const __attribute__((address_space(1))) unsigned int*)ks,               \
            (__attribute__((address_space(3))) unsigned int*)&kvs[buf][0][rbase * 64], 16, 0, 0); \
        __builtin_amdgcn_global_load_lds(                                            \
            (const __attribute__((address_space(1))) unsigned int*)vs,               \
            (__attribute__((address_space(3))) unsigned int*)&kvs[buf][1][rbase * 64], 16, 0, 0); \
    }

    STAGE(0, kbeg)

    int cur = 0;
    for (int k0 = kbeg; k0 < kend; k0 += 64, cur ^= 1) {
        __syncthreads();
        bool active = (k0 + 63 >= qbase - WIN) && (k0 <= qbase + 15 + WIN);
        short8 kc[4][2];
        if (active) {
#pragma unroll
            for (int nt = 0; nt < 4; ++nt)
#pragma unroll
                for (int hh = 0; hh < 2; ++hh) {
                    int row = nt * 16 + lc;
                    kc[nt][hh] = *(const short8*)(&kvs[cur][0][row * 64 + (((hh * 4 + lg) ^ (row & 7)) * 8)]);
                }
        }
        if (k0 + 64 < kend) STAGE(cur ^ 1, k0 + 64)
        if (!active) continue;

        bool fullband = (k0 >= qbase - 241) && (k0 <= qbase + 193);

        floatx4 sc[4];
#pragma unroll
        for (int nt = 0; nt < 4; ++nt) {
            floatx4 z = (floatx4)0.0f;
            z = __builtin_amdgcn_mfma_f32_16x16x32_bf16(qf[0], kc[nt][0], z, 0, 0, 0);
            sc[nt] = __builtin_amdgcn_mfma_f32_16x16x32_bf16(qf[1], kc[nt][1], z, 0, 0, 0);
        }
#pragma unroll
        for (int nt = 0; nt < 4; ++nt)
#pragma unroll
            for (int r = 0; r < 4; ++r)
                sc[nt][r] = __expf(sc[nt][r]);
        if (!fullband) {
#pragma unroll
            for (int nt = 0; nt < 4; ++nt) {
                int kk = k0 + nt * 16 + lc;
#pragma unroll
                for (int r = 0; r < 4; ++r) {
                    int dq = (qbase + lg * 4 + r) - kk;
                    if (dq > WIN || dq < -WIN) sc[nt][r] = 0.0f;
                }
            }
        }
#pragma unroll
        for (int r = 0; r < 4; ++r)
            lsum[r] += (sc[0][r] + sc[1][r]) + (sc[2][r] + sc[3][r]);
#pragma unroll
        for (int nt = 0; nt < 4; ++nt)
#pragma unroll
            for (int r = 0; r < 4; ++r)
                Ps[wv][lg * 4 + r][nt * 16 + lc] = f2bf(sc[nt][r]);

        short8 pa0 = *(const short8*)(&Ps[wv][lc][lg * 8]);
        short8 pa1 = *(const short8*)(&Ps[wv][lc][32 + lg * 8]);
#pragma unroll
        for (int nt2 = 0; nt2 < 4; ++nt2) {
            int row = nt2 * 16 + lc;
            short8 vf0 = *(const short8*)(&kvs[cur][1][row * 64 + (((0 + lg) ^ (row & 7)) * 8)]);
            short8 vf1 = *(const short8*)(&kvs[cur][1][row * 64 + (((4 + lg) ^ (row & 7)) * 8)]);
            o[nt2] = __builtin_amdgcn_mfma_f32_16x16x32_bf16(pa0, vf0, o[nt2], 0, 0, 0);
            o[nt2] = __builtin_amdgcn_mfma_f32_16x16x32_bf16(pa1, vf1, o[nt2], 0, 0, 0);
        }
    }

#pragma unroll
    for (int r = 0; r < 4; ++r) {
        float rs = lsum[r];
#pragma unroll
        for (int off = 1; off < 16; off <<= 1)
            rs += __shfl_xor(rs, off, 64);
        lsum[r] = 1.0f / rs;
    }
#pragma unroll
    for (int nt2 = 0; nt2 < 4; ++nt2)
#pragma unroll
        for (int r = 0; r < 4; ++r) {
            int q = qbase + lg * 4 + r;
            int d = nt2 * 16 + lc;
            outp[((size_t)b * SS + q) * EE + h * HD + d] = o[nt2][r] * lsum[r];
        }
}

extern "C" void kernel_launch(void* const* d_in, const int* in_sizes, int n_in,
                              void* d_out, int out_size, void* d_ws, size_t ws_size,
                              hipStream_t stream) {
    const float* X  = (const float*)d_in[0];
    const float* Wq = (const float*)d_in[1];
    const float* bq = (const float*)d_in[2];
    const float* Wk = (const float*)d_in[3];
    const float* bk = (const float*)d_in[4];
    const float* Wv = (const float*)d_in[5];
    const float* bv = (const float*)d_in[6];

    const size_t qkv_elems = (size_t)BB * NH * SS * HD;   // 8,388,608 bf16 each
    unsigned short* Qw = (unsigned short*)d_ws;
    unsigned short* Kw = Qw + qkv_elems;
    unsigned short* Vw = Kw + qkv_elems;

    unsigned short* cvt = (unsigned short*)d_out;
    const unsigned short* Xb = cvt;
    const unsigned short* WbAll = cvt + 8388608;

    cvt_kernel<<<dim3(11264), 256, 0, stream>>>(X, Wq, Wk, Wv, cvt);
    qkv_gemm4<<<dim3(1536), 256, 0, stream>>>(
        Xb, WbAll, bq, bk, bv, Qw, Kw, Vw);
    swa_kernel<<<dim3(1024), 512, 0, stream>>>(Qw, Kw, Vw, (float*)d_out);
}

// Round 7
// 187.535 us; speedup vs baseline: 2.2953x; 1.0262x over previous
//
#include <hip/hip_runtime.h>

#define NH 16
#define HD 64
#define WIN 256
#define BB 2
#define SS 4096
#define EE 1024

typedef __attribute__((ext_vector_type(8))) short short8;
typedef __attribute__((ext_vector_type(4))) float floatx4;
typedef __attribute__((ext_vector_type(16))) float floatx16;
typedef __attribute__((ext_vector_type(4))) unsigned short ushort4v;
typedef __attribute__((ext_vector_type(4))) unsigned int uint4v;

__device__ inline unsigned short f2bf(float f) {
    unsigned u = __builtin_bit_cast(unsigned, f);
    u += 0x7fffu + ((u >> 16) & 1u);
    return (unsigned short)(u >> 16);
}

// ---------------- pass 0: f32 -> bf16 convert of X and W's into d_out scratch
__global__ __launch_bounds__(256)
void cvt_kernel(const float* __restrict__ X,
                const float* __restrict__ W0,
                const float* __restrict__ W1,
                const float* __restrict__ W2,
                unsigned short* __restrict__ out)
{
    size_t idx = (size_t)blockIdx.x * 256 + threadIdx.x;   // float4 index
    const size_t X4 = 2097152, W4 = 262144;                // float4 counts
    const float* src; unsigned short* dst; size_t off;
    if (idx < X4)                { src = X;  dst = out;            off = idx; }
    else if (idx < X4 + W4)      { src = W0; dst = out + 8388608;  off = idx - X4; }
    else if (idx < X4 + 2 * W4)  { src = W1; dst = out + 9437184;  off = idx - X4 - W4; }
    else                         { src = W2; dst = out + 10485760; off = idx - X4 - 2 * W4; }
    float4 v = ((const float4*)src)[off];
    ushort4 u;
    u.x = f2bf(v.x); u.y = f2bf(v.y); u.z = f2bf(v.z); u.w = f2bf(v.w);
    ((ushort4*)dst)[off] = u;
}

// ---------------- pass 1: bf16 GEMM, BK=64, LDS-transposed coalesced epilogue.
// Proven round-0 configuration (63.5us at full clock, 813 TF): 128x128 tile,
// 4 waves, 2-barrier K-loop, global_load_lds staging. DO NOT restructure:
// 256^2/8-phase (89us), BM=256/8-wave (VGPR spill, 300us), BK=32 (76us at
// full clock) all regressed.
__global__ __launch_bounds__(256, 4)
void qkv_gemm4(const unsigned short* __restrict__ Xb,
               const unsigned short* __restrict__ WbAll,
               const float* __restrict__ b0,
               const float* __restrict__ b1,
               const float* __restrict__ b2,
               unsigned short* __restrict__ Qo,
               unsigned short* __restrict__ Ko,
               unsigned short* __restrict__ Vo)
{
    const int id = blockIdx.x;           // 0..1535
    const int xcd = id & 7;
    const int rest = id >> 3;            // 0..191
    const int ytile = xcd + 8 * (rest & 7);   // 0..63, ytile%8 == xcd
    const int nm = rest >> 3;            // 0..23
    const int ntile = nm & 7;            // 0..7
    const int mode = nm >> 3;            // 0..2

    const unsigned short* Wm = WbAll + (size_t)mode * 1048576;
    const float* bm = (mode == 0) ? b0 : (mode == 1) ? b1 : b2;
    unsigned short* outp = (mode == 0) ? Qo : (mode == 1) ? Ko : Vo;

    const int m0 = ytile * 128;
    const int n0 = ntile * 128;
    const int t = threadIdx.x;
    const int lane = t & 63;
    const int wv = t >> 6;
    const int wm = wv >> 1, wn = wv & 1;
    const int lg = lane >> 4, lc = lane & 15;

    __shared__ __attribute__((aligned(16))) unsigned short smem[16384];
    unsigned short* As[2] = { smem, smem + 4096 };
    unsigned short* Bs[2] = { smem + 8192, smem + 12288 };

    const int srow = lane >> 2;
    const int scol = (lane & 3) * 8;

    floatx4 acc[4][4];
#pragma unroll
    for (int i = 0; i < 4; ++i)
#pragma unroll
        for (int j = 0; j < 4; ++j)
            acc[i][j] = (floatx4)0.0f;

    for (int kt = 0; kt < EE; kt += 64) {
        if (kt) __syncthreads();
#pragma unroll
        for (int half = 0; half < 2; ++half) {
#pragma unroll
            for (int seg = 0; seg < 2; ++seg) {
                int r0 = wv * 32 + seg * 16;
                const unsigned short* asrc =
                    Xb + (size_t)(m0 + r0 + srow) * EE + kt + half * 32 + scol;
                const unsigned short* bsrc =
                    Wm + (size_t)(n0 + r0 + srow) * EE + kt + half * 32 + scol;
                __builtin_amdgcn_global_load_lds(
                    (const __attribute__((address_space(1))) unsigned int*)asrc,
                    (__attribute__((address_space(3))) unsigned int*)&As[half][r0 * 32], 16, 0, 0);
                __builtin_amdgcn_global_load_lds(
                    (const __attribute__((address_space(1))) unsigned int*)bsrc,
                    (__attribute__((address_space(3))) unsigned int*)&Bs[half][r0 * 32], 16, 0, 0);
            }
        }
        __syncthreads();

#pragma unroll
        for (int half = 0; half < 2; ++half) {
            short8 af[4], bfr[4];
#pragma unroll
            for (int mt = 0; mt < 4; ++mt)
                af[mt] = *(const short8*)(&As[half][(wm * 64 + mt * 16 + lc) * 32 + lg * 8]);
#pragma unroll
            for (int nt = 0; nt < 4; ++nt)
                bfr[nt] = *(const short8*)(&Bs[half][(wn * 64 + nt * 16 + lc) * 32 + lg * 8]);
#pragma unroll
            for (int mt = 0; mt < 4; ++mt)
#pragma unroll
                for (int nt = 0; nt < 4; ++nt)
                    acc[mt][nt] = __builtin_amdgcn_mfma_f32_16x16x32_bf16(
                        af[mt], bfr[nt], acc[mt][nt], 0, 0, 0);
        }
    }

    const int CST = 136;
    const float qscale = (mode == 0) ? 0.125f : 1.0f;
#pragma unroll
    for (int p = 0; p < 2; ++p) {
        __syncthreads();
        if (mode < 2) {
            if (wm == p) {
#pragma unroll
                for (int nt = 0; nt < 4; ++nt) {
                    float bias = bm[n0 + wn * 64 + nt * 16 + lc];
#pragma unroll
                    for (int mt = 0; mt < 4; ++mt)
#pragma unroll
                        for (int r = 0; r < 4; ++r) {
                            int ml = mt * 16 + lg * 4 + r;
                            int nl = wn * 64 + nt * 16 + lc;
                            smem[ml * CST + nl] = f2bf((acc[mt][nt][r] + bias) * qscale);
                        }
                }
            }
        } else {
            if (wn == p) {
#pragma unroll
                for (int nt = 0; nt < 4; ++nt) {
                    float bias = bm[n0 + p * 64 + nt * 16 + lc];
#pragma unroll
                    for (int mt = 0; mt < 4; ++mt) {
                        ushort4v pk;
#pragma unroll
                        for (int r = 0; r < 4; ++r)
                            pk[r] = f2bf(acc[mt][nt][r] + bias);
                        int nl = nt * 16 + lc;
                        int col = wm * 64 + mt * 16 + lg * 4;
                        *(ushort4v*)(&smem[nl * CST + col]) = pk;
                    }
                }
            }
        }
        __syncthreads();
#pragma unroll
        for (int q = 0; q < 4; ++q) {
            int c = q * 256 + t;
            int row = c >> 4;
            int j = c & 15;
            uint4 val = *(const uint4*)(&smem[row * CST + j * 8]);
            if (mode < 2) {
                int m = m0 + p * 64 + row;
                int bb = m >> 12, s = m & (SS - 1);
                int n = n0 + j * 8;
                int hh = n >> 6, dd = n & 63;
                *(uint4*)(outp + (((size_t)bb * NH + hh) * SS + s) * HD + dd) = val;
            } else {
                int n = n0 + p * 64 + row;
                int hh = n >> 6, dd = n & 63;
                int m = m0 + j * 8;
                int bb = m >> 12, s = m & (SS - 1);
                *(uint4*)(outp + (((size_t)bb * NH + hh) * HD + dd) * SS + s) = val;
            }
        }
    }
}

// ---------------- pass 2: banded flash attention, T12 structure.
// 4 waves x 32 q-rows, 32x32x16 MFMA, SWAPPED QK^T (mfma(K,Q)) so each lane
// holds P only for q=lane&31. P->A-fragment conversion is pure VALU:
// 8x v_cvt_pk_bf16_f32 + 4x v_permlane32_swap_b32 per 32-k subtile
// (pairing: swap(j0,j2)->{d0,d2}, swap(j1,j3)->{d1,d3}). The Ps LDS buffer
// and its serial write->read round-trip (~40% of LDS-pipe load) are GONE.
// LDS 32.5KB -> 4 blocks/CU; grid 1024 = one residency round.
__global__ __launch_bounds__(256, 4)
void swa_kernel(const unsigned short* __restrict__ Qp_,
                const unsigned short* __restrict__ Kp_,
                const unsigned short* __restrict__ Vp_,
                float* __restrict__ outp)
{
    const int id = blockIdx.x;            // 0..1023
    const int xcd = id & 7;
    const int idx = id >> 3;              // 0..127
    const int bh = xcd + 8 * (idx >> 5);  // 0..31, bh%8 == xcd (L2 locality)
    const int q0 = (idx & 31) * 128;
    const int b = bh >> 4;
    const int h = bh & 15;
    const int t = threadIdx.x, lane = t & 63, wv = t >> 6;   // 4 waves
    const int l31 = lane & 31, hf = lane >> 5;
    const size_t bhs = (size_t)b * NH + h;
    const unsigned short* Qp = Qp_ + bhs * (size_t)SS * HD;
    const unsigned short* Kp = Kp_ + bhs * (size_t)SS * HD;
    const unsigned short* Vp = Vp_ + bhs * (size_t)HD * SS;
    const int qbase = q0 + wv * 32;       // 32 q-rows per wave

    // Q as B-fragments: qf[dc] = Q[qbase+l31][dc*16 + hf*8 + e]
    short8 qf[4];
#pragma unroll
    for (int dc = 0; dc < 4; ++dc)
        qf[dc] = *(const short8*)(Qp + (size_t)(qbase + l31) * HD + dc * 16 + hf * 8);

    floatx16 o0 = (floatx16)0.0f;   // O[q][d=0..31],  d = l31
    floatx16 o1 = (floatx16)0.0f;   // O[q][d=32..63]
    float lsq = 0.0f;               // sum of P over all k, for q = l31

    __shared__ __attribute__((aligned(16))) unsigned short kvs[2][2][4096];
    __shared__ float lsums[4][32];

    const int kbeg = (q0 >= WIN) ? (q0 - WIN) : 0;
    const int kend = (q0 + 128 + WIN <= SS) ? (q0 + 128 + WIN) : SS;

    const int sr = lane >> 3;
    const int sj = lane & 7;
    const int swz = (sj ^ sr) * 8;

#define STAGE(buf, k0_)                                                              \
    {                                                                                \
        _Pragma("unroll")                                                            \
        for (int i = 0; i < 2; ++i) {                                                \
            int rbase = 16 * wv + i * 8;                                             \
            const unsigned short* ks = Kp + (size_t)((k0_) + rbase + sr) * HD + swz; \
            const unsigned short* vs = Vp + (size_t)(rbase + sr) * SS + (k0_) + swz; \
            __builtin_amdgcn_global_load_lds(                                        \
                (const __attribute__((address_space(1))) unsigned int*)ks,           \
                (__attribute__((address_space(3))) unsigned int*)&kvs[buf][0][rbase * 64], 16, 0, 0); \
            __builtin_amdgcn_global_load_lds(                                        \
                (const __attribute__((address_space(1))) unsigned int*)vs,           \
                (__attribute__((address_space(3))) unsigned int*)&kvs[buf][1][rbase * 64], 16, 0, 0); \
        }                                                                            \
    }

    STAGE(0, kbeg)

    int cur = 0;
    for (int k0 = kbeg; k0 < kend; k0 += 64, cur ^= 1) {
        __syncthreads();
        if (k0 + 64 < kend) STAGE(cur ^ 1, k0 + 64)
        bool active = (k0 + 63 >= qbase - WIN) && (k0 <= qbase + 31 + WIN);
        if (!active) continue;
        bool fullband = (k0 >= qbase - 225) && (k0 <= qbase + 193);

#pragma unroll
        for (int ks = 0; ks < 2; ++ks) {
            // K as A-fragments: kc[dc] = K[k0+ks*32+l31][dc*16 + hf*8 + e]
            short8 kc[4];
#pragma unroll
            for (int dc = 0; dc < 4; ++dc) {
                int row = ks * 32 + l31;
                kc[dc] = *(const short8*)(&kvs[cur][0][row * 64 + (((dc * 2 + hf) ^ (row & 7)) * 8)]);
            }
            // swapped QK^T: D[k_local][q], k_local = (r&3)+8*(r>>2)+4*hf, q = l31
            floatx16 z = (floatx16)0.0f;
            z = __builtin_amdgcn_mfma_f32_32x32x16_bf16(kc[0], qf[0], z, 0, 0, 0);
            z = __builtin_amdgcn_mfma_f32_32x32x16_bf16(kc[1], qf[1], z, 0, 0, 0);
            z = __builtin_amdgcn_mfma_f32_32x32x16_bf16(kc[2], qf[2], z, 0, 0, 0);
            z = __builtin_amdgcn_mfma_f32_32x32x16_bf16(kc[3], qf[3], z, 0, 0, 0);

            float p[16];
#pragma unroll
            for (int r = 0; r < 16; ++r)
                p[r] = __expf(z[r]);
            if (!fullband) {
#pragma unroll
                for (int r = 0; r < 16; ++r) {
                    int kk = k0 + ks * 32 + (r & 3) + 8 * (r >> 2) + 4 * hf;
                    int dq = (qbase + l31) - kk;
                    if (dq > WIN || dq < -WIN) p[r] = 0.0f;
                }
            }
#pragma unroll
            for (int r = 0; r < 16; ++r)
                lsq += p[r];

            // pack to bf16 pairs: j_m = (k = base+2m, base+2m+1), base = ks*32+4*hf-block
            unsigned int j0, j1, j2, j3, j4, j5, j6, j7;
            asm("v_cvt_pk_bf16_f32 %0, %1, %2" : "=v"(j0) : "v"(p[0]),  "v"(p[1]));
            asm("v_cvt_pk_bf16_f32 %0, %1, %2" : "=v"(j1) : "v"(p[2]),  "v"(p[3]));
            asm("v_cvt_pk_bf16_f32 %0, %1, %2" : "=v"(j2) : "v"(p[4]),  "v"(p[5]));
            asm("v_cvt_pk_bf16_f32 %0, %1, %2" : "=v"(j3) : "v"(p[6]),  "v"(p[7]));
            asm("v_cvt_pk_bf16_f32 %0, %1, %2" : "=v"(j4) : "v"(p[8]),  "v"(p[9]));
            asm("v_cvt_pk_bf16_f32 %0, %1, %2" : "=v"(j5) : "v"(p[10]), "v"(p[11]));
            asm("v_cvt_pk_bf16_f32 %0, %1, %2" : "=v"(j6) : "v"(p[12]), "v"(p[13]));
            asm("v_cvt_pk_bf16_f32 %0, %1, %2" : "=v"(j7) : "v"(p[14]), "v"(p[15]));
            // redistribute halves: after swap, {j0,j1,j2,j3} = A-frag dwords for
            // k-chunk ks*32+0..15, {j4,j5,j6,j7} for ks*32+16..31
            asm("v_permlane32_swap_b32 %0, %1" : "+v"(j0), "+v"(j2));
            asm("v_permlane32_swap_b32 %0, %1" : "+v"(j1), "+v"(j3));
            asm("v_permlane32_swap_b32 %0, %1" : "+v"(j4), "+v"(j6));
            asm("v_permlane32_swap_b32 %0, %1" : "+v"(j5), "+v"(j7));
            short8 pa0 = __builtin_bit_cast(short8, (uint4v){j0, j1, j2, j3});
            short8 pa1 = __builtin_bit_cast(short8, (uint4v){j4, j5, j6, j7});

            // PV: O[q][d] += P[q][k] * V[d][k]  (V as B-fragment)
            {
                int row = l31;                 // d 0..31
                short8 vf0 = *(const short8*)(&kvs[cur][1][row * 64 + (((ks * 4 + 0 + hf) ^ (row & 7)) * 8)]);
                short8 vf1 = *(const short8*)(&kvs[cur][1][row * 64 + (((ks * 4 + 2 + hf) ^ (row & 7)) * 8)]);
                o0 = __builtin_amdgcn_mfma_f32_32x32x16_bf16(pa0, vf0, o0, 0, 0, 0);
                o0 = __builtin_amdgcn_mfma_f32_32x32x16_bf16(pa1, vf1, o0, 0, 0, 0);
            }
            {
                int row = 32 + l31;            // d 32..63
                short8 vf0 = *(const short8*)(&kvs[cur][1][row * 64 + (((ks * 4 + 0 + hf) ^ (row & 7)) * 8)]);
                short8 vf1 = *(const short8*)(&kvs[cur][1][row * 64 + (((ks * 4 + 2 + hf) ^ (row & 7)) * 8)]);
                o1 = __builtin_amdgcn_mfma_f32_32x32x16_bf16(pa0, vf0, o1, 0, 0, 0);
                o1 = __builtin_amdgcn_mfma_f32_32x32x16_bf16(pa1, vf1, o1, 0, 0, 0);
            }
        }
    }

    // denominator: lanes l and l+32 hold partial sums for the same q=l31
    float tot = lsq + __shfl_xor(lsq, 32, 64);
    if (lane < 32) lsums[wv][l31] = 1.0f / tot;

#pragma unroll
    for (int r = 0; r < 16; ++r) {
        int qloc = (r & 3) + 8 * (r >> 2) + 4 * hf;
        float inv = lsums[wv][qloc];
        int q = qbase + qloc;
        float* orow = outp + ((size_t)b * SS + q) * EE + h * HD;
        orow[l31] = o0[r] * inv;
        orow[32 + l31] = o1[r] * inv;
    }
}

extern "C" void kernel_launch(void* const* d_in, const int* in_sizes, int n_in,
                              void* d_out, int out_size, void* d_ws, size_t ws_size,
                              hipStream_t stream) {
    const float* X  = (const float*)d_in[0];
    const float* Wq = (const float*)d_in[1];
    const float* bq = (const float*)d_in[2];
    const float* Wk = (const float*)d_in[3];
    const float* bk = (const float*)d_in[4];
    const float* Wv = (const float*)d_in[5];
    const float* bv = (const float*)d_in[6];

    const size_t qkv_elems = (size_t)BB * NH * SS * HD;   // 8,388,608 bf16 each
    unsigned short* Qw = (unsigned short*)d_ws;
    unsigned short* Kw = Qw + qkv_elems;
    unsigned short* Vw = Kw + qkv_elems;

    unsigned short* cvt = (unsigned short*)d_out;
    const unsigned short* Xb = cvt;
    const unsigned short* WbAll = cvt + 8388608;

    cvt_kernel<<<dim3(11264), 256, 0, stream>>>(X, Wq, Wk, Wv, cvt);
    qkv_gemm4<<<dim3(1536), 256, 0, stream>>>(
        Xb, WbAll, bq, bk, bv, Qw, Kw, Vw);
    swa_kernel<<<dim3(1024), 256, 0, stream>>>(Qw, Kw, Vw, (float*)d_out);
}

// Round 8
// 182.831 us; speedup vs baseline: 2.3544x; 1.0257x over previous
//
#include <hip/hip_runtime.h>

#define NH 16
#define HD 64
#define WIN 256
#define BB 2
#define SS 4096
#define EE 1024

typedef __attribute__((ext_vector_type(8))) short short8;
typedef __attribute__((ext_vector_type(4))) float floatx4;
typedef __attribute__((ext_vector_type(16))) float floatx16;
typedef __attribute__((ext_vector_type(4))) unsigned short ushort4v;
typedef __attribute__((ext_vector_type(4))) unsigned int uint4v;

__device__ inline unsigned short f2bf(float f) {
    unsigned u = __builtin_bit_cast(unsigned, f);
    u += 0x7fffu + ((u >> 16) & 1u);
    return (unsigned short)(u >> 16);
}

// ---------------- pass 0: f32 -> bf16 convert of X and W's into d_out scratch
__global__ __launch_bounds__(256)
void cvt_kernel(const float* __restrict__ X,
                const float* __restrict__ W0,
                const float* __restrict__ W1,
                const float* __restrict__ W2,
                unsigned short* __restrict__ out)
{
    size_t idx = (size_t)blockIdx.x * 256 + threadIdx.x;   // float4 index
    const size_t X4 = 2097152, W4 = 262144;                // float4 counts
    const float* src; unsigned short* dst; size_t off;
    if (idx < X4)                { src = X;  dst = out;            off = idx; }
    else if (idx < X4 + W4)      { src = W0; dst = out + 8388608;  off = idx - X4; }
    else if (idx < X4 + 2 * W4)  { src = W1; dst = out + 9437184;  off = idx - X4 - W4; }
    else                         { src = W2; dst = out + 10485760; off = idx - X4 - 2 * W4; }
    float4 v = ((const float4*)src)[off];
    ushort4 u;
    u.x = f2bf(v.x); u.y = f2bf(v.y); u.z = f2bf(v.z); u.w = f2bf(v.w);
    ((ushort4*)dst)[off] = u;
}

// ---------------- pass 1: bf16 GEMM, BK=64, LDS-transposed coalesced epilogue.
// Proven round-0 configuration (63.5us at full clock, 813 TF): 128x128 tile,
// 4 waves, 2-barrier K-loop, global_load_lds staging. FROZEN: 256^2/8-phase
// (89us), BM=256/8-wave (VGPR spill, 300us), BK=32 (76us) all regressed.
__global__ __launch_bounds__(256, 4)
void qkv_gemm4(const unsigned short* __restrict__ Xb,
               const unsigned short* __restrict__ WbAll,
               const float* __restrict__ b0,
               const float* __restrict__ b1,
               const float* __restrict__ b2,
               unsigned short* __restrict__ Qo,
               unsigned short* __restrict__ Ko,
               unsigned short* __restrict__ Vo)
{
    const int id = blockIdx.x;           // 0..1535
    const int xcd = id & 7;
    const int rest = id >> 3;            // 0..191
    const int ytile = xcd + 8 * (rest & 7);   // 0..63, ytile%8 == xcd
    const int nm = rest >> 3;            // 0..23
    const int ntile = nm & 7;            // 0..7
    const int mode = nm >> 3;            // 0..2

    const unsigned short* Wm = WbAll + (size_t)mode * 1048576;
    const float* bm = (mode == 0) ? b0 : (mode == 1) ? b1 : b2;
    unsigned short* outp = (mode == 0) ? Qo : (mode == 1) ? Ko : Vo;

    const int m0 = ytile * 128;
    const int n0 = ntile * 128;
    const int t = threadIdx.x;
    const int lane = t & 63;
    const int wv = t >> 6;
    const int wm = wv >> 1, wn = wv & 1;
    const int lg = lane >> 4, lc = lane & 15;

    __shared__ __attribute__((aligned(16))) unsigned short smem[16384];
    unsigned short* As[2] = { smem, smem + 4096 };
    unsigned short* Bs[2] = { smem + 8192, smem + 12288 };

    const int srow = lane >> 2;
    const int scol = (lane & 3) * 8;

    floatx4 acc[4][4];
#pragma unroll
    for (int i = 0; i < 4; ++i)
#pragma unroll
        for (int j = 0; j < 4; ++j)
            acc[i][j] = (floatx4)0.0f;

    for (int kt = 0; kt < EE; kt += 64) {
        if (kt) __syncthreads();
#pragma unroll
        for (int half = 0; half < 2; ++half) {
#pragma unroll
            for (int seg = 0; seg < 2; ++seg) {
                int r0 = wv * 32 + seg * 16;
                const unsigned short* asrc =
                    Xb + (size_t)(m0 + r0 + srow) * EE + kt + half * 32 + scol;
                const unsigned short* bsrc =
                    Wm + (size_t)(n0 + r0 + srow) * EE + kt + half * 32 + scol;
                __builtin_amdgcn_global_load_lds(
                    (const __attribute__((address_space(1))) unsigned int*)asrc,
                    (__attribute__((address_space(3))) unsigned int*)&As[half][r0 * 32], 16, 0, 0);
                __builtin_amdgcn_global_load_lds(
                    (const __attribute__((address_space(1))) unsigned int*)bsrc,
                    (__attribute__((address_space(3))) unsigned int*)&Bs[half][r0 * 32], 16, 0, 0);
            }
        }
        __syncthreads();

#pragma unroll
        for (int half = 0; half < 2; ++half) {
            short8 af[4], bfr[4];
#pragma unroll
            for (int mt = 0; mt < 4; ++mt)
                af[mt] = *(const short8*)(&As[half][(wm * 64 + mt * 16 + lc) * 32 + lg * 8]);
#pragma unroll
            for (int nt = 0; nt < 4; ++nt)
                bfr[nt] = *(const short8*)(&Bs[half][(wn * 64 + nt * 16 + lc) * 32 + lg * 8]);
#pragma unroll
            for (int mt = 0; mt < 4; ++mt)
#pragma unroll
                for (int nt = 0; nt < 4; ++nt)
                    acc[mt][nt] = __builtin_amdgcn_mfma_f32_16x16x32_bf16(
                        af[mt], bfr[nt], acc[mt][nt], 0, 0, 0);
        }
    }

    const int CST = 136;
    const float qscale = (mode == 0) ? 0.125f : 1.0f;
#pragma unroll
    for (int p = 0; p < 2; ++p) {
        __syncthreads();
        if (mode < 2) {
            if (wm == p) {
#pragma unroll
                for (int nt = 0; nt < 4; ++nt) {
                    float bias = bm[n0 + wn * 64 + nt * 16 + lc];
#pragma unroll
                    for (int mt = 0; mt < 4; ++mt)
#pragma unroll
                        for (int r = 0; r < 4; ++r) {
                            int ml = mt * 16 + lg * 4 + r;
                            int nl = wn * 64 + nt * 16 + lc;
                            smem[ml * CST + nl] = f2bf((acc[mt][nt][r] + bias) * qscale);
                        }
                }
            }
        } else {
            if (wn == p) {
#pragma unroll
                for (int nt = 0; nt < 4; ++nt) {
                    float bias = bm[n0 + p * 64 + nt * 16 + lc];
#pragma unroll
                    for (int mt = 0; mt < 4; ++mt) {
                        ushort4v pk;
#pragma unroll
                        for (int r = 0; r < 4; ++r)
                            pk[r] = f2bf(acc[mt][nt][r] + bias);
                        int nl = nt * 16 + lc;
                        int col = wm * 64 + mt * 16 + lg * 4;
                        *(ushort4v*)(&smem[nl * CST + col]) = pk;
                    }
                }
            }
        }
        __syncthreads();
#pragma unroll
        for (int q = 0; q < 4; ++q) {
            int c = q * 256 + t;
            int row = c >> 4;
            int j = c & 15;
            uint4 val = *(const uint4*)(&smem[row * CST + j * 8]);
            if (mode < 2) {
                int m = m0 + p * 64 + row;
                int bb = m >> 12, s = m & (SS - 1);
                int n = n0 + j * 8;
                int hh = n >> 6, dd = n & 63;
                *(uint4*)(outp + (((size_t)bb * NH + hh) * SS + s) * HD + dd) = val;
            } else {
                int n = n0 + p * 64 + row;
                int hh = n >> 6, dd = n & 63;
                int m = m0 + j * 8;
                int bb = m >> 12, s = m & (SS - 1);
                *(uint4*)(outp + (((size_t)bb * NH + hh) * HD + dd) * SS + s) = val;
            }
        }
    }
}

// ---------------- pass 2: banded flash attention, T12 structure (R7: -5us).
// 4 waves x 32 q-rows, 32x32x16 MFMA, swapped QK^T; P stays in registers
// (cvt_pk + permlane32_swap). R8 additions: T5 setprio around MFMA clusters
// (4 independent blocks/CU = the m191 regime where it measured +4-7%),
// single-unsigned-compare band mask, nontemporal output stores.
__global__ __launch_bounds__(256, 4)
void swa_kernel(const unsigned short* __restrict__ Qp_,
                const unsigned short* __restrict__ Kp_,
                const unsigned short* __restrict__ Vp_,
                float* __restrict__ outp)
{
    const int id = blockIdx.x;            // 0..1023
    const int xcd = id & 7;
    const int idx = id >> 3;              // 0..127
    const int bh = xcd + 8 * (idx >> 5);  // 0..31, bh%8 == xcd (L2 locality)
    const int q0 = (idx & 31) * 128;
    const int b = bh >> 4;
    const int h = bh & 15;
    const int t = threadIdx.x, lane = t & 63, wv = t >> 6;   // 4 waves
    const int l31 = lane & 31, hf = lane >> 5;
    const size_t bhs = (size_t)b * NH + h;
    const unsigned short* Qp = Qp_ + bhs * (size_t)SS * HD;
    const unsigned short* Kp = Kp_ + bhs * (size_t)SS * HD;
    const unsigned short* Vp = Vp_ + bhs * (size_t)HD * SS;
    const int qbase = q0 + wv * 32;       // 32 q-rows per wave

    // Q as B-fragments: qf[dc] = Q[qbase+l31][dc*16 + hf*8 + e]
    short8 qf[4];
#pragma unroll
    for (int dc = 0; dc < 4; ++dc)
        qf[dc] = *(const short8*)(Qp + (size_t)(qbase + l31) * HD + dc * 16 + hf * 8);

    floatx16 o0 = (floatx16)0.0f;   // O[q][d=0..31],  d = l31
    floatx16 o1 = (floatx16)0.0f;   // O[q][d=32..63]
    float lsq = 0.0f;               // sum of P over all k, for q = l31

    __shared__ __attribute__((aligned(16))) unsigned short kvs[2][2][4096];
    __shared__ float lsums[4][32];

    const int kbeg = (q0 >= WIN) ? (q0 - WIN) : 0;
    const int kend = (q0 + 128 + WIN <= SS) ? (q0 + 128 + WIN) : SS;

    const int sr = lane >> 3;
    const int sj = lane & 7;
    const int swz = (sj ^ sr) * 8;

#define STAGE(buf, k0_)                                                              \
    {                                                                                \
        _Pragma("unroll")                                                            \
        for (int i = 0; i < 2; ++i) {                                                \
            int rbase = 16 * wv + i * 8;                                             \
            const unsigned short* ks = Kp + (size_t)((k0_) + rbase + sr) * HD + swz; \
            const unsigned short* vs = Vp + (size_t)(rbase + sr) * SS + (k0_) + swz; \
            __builtin_amdgcn_global_load_lds(                                        \
                (const __attribute__((address_space(1))) unsigned int*)ks,           \
                (__attribute__((address_space(3))) unsigned int*)&kvs[buf][0][rbase * 64], 16, 0, 0); \
            __builtin_amdgcn_global_load_lds(                                        \
                (const __attribute__((address_space(1))) unsigned int*)vs,           \
                (__attribute__((address_space(3))) unsigned int*)&kvs[buf][1][rbase * 64], 16, 0, 0); \
        }                                                                            \
    }

    STAGE(0, kbeg)

    int cur = 0;
    for (int k0 = kbeg; k0 < kend; k0 += 64, cur ^= 1) {
        __syncthreads();
        if (k0 + 64 < kend) STAGE(cur ^ 1, k0 + 64)
        bool active = (k0 + 63 >= qbase - WIN) && (k0 <= qbase + 31 + WIN);
        if (!active) continue;
        bool fullband = (k0 >= qbase - 225) && (k0 <= qbase + 193);

#pragma unroll
        for (int ks = 0; ks < 2; ++ks) {
            // K as A-fragments: kc[dc] = K[k0+ks*32+l31][dc*16 + hf*8 + e]
            short8 kc[4];
#pragma unroll
            for (int dc = 0; dc < 4; ++dc) {
                int row = ks * 32 + l31;
                kc[dc] = *(const short8*)(&kvs[cur][0][row * 64 + (((dc * 2 + hf) ^ (row & 7)) * 8)]);
            }
            // swapped QK^T: D[k_local][q], k_local = (r&3)+8*(r>>2)+4*hf, q = l31
            floatx16 z = (floatx16)0.0f;
            __builtin_amdgcn_s_setprio(1);
            z = __builtin_amdgcn_mfma_f32_32x32x16_bf16(kc[0], qf[0], z, 0, 0, 0);
            z = __builtin_amdgcn_mfma_f32_32x32x16_bf16(kc[1], qf[1], z, 0, 0, 0);
            z = __builtin_amdgcn_mfma_f32_32x32x16_bf16(kc[2], qf[2], z, 0, 0, 0);
            z = __builtin_amdgcn_mfma_f32_32x32x16_bf16(kc[3], qf[3], z, 0, 0, 0);
            __builtin_amdgcn_s_setprio(0);

            float p[16];
#pragma unroll
            for (int r = 0; r < 16; ++r)
                p[r] = __expf(z[r]);
            if (!fullband) {
#pragma unroll
                for (int r = 0; r < 16; ++r) {
                    int kk = k0 + ks * 32 + (r & 3) + 8 * (r >> 2) + 4 * hf;
                    int dq = (qbase + l31) - kk;
                    if ((unsigned)(dq + WIN) > 2u * WIN) p[r] = 0.0f;
                }
            }
#pragma unroll
            for (int r = 0; r < 16; ++r)
                lsq += p[r];

            // pack to bf16 pairs, then redistribute halves across lane<32/>=32
            unsigned int j0, j1, j2, j3, j4, j5, j6, j7;
            asm("v_cvt_pk_bf16_f32 %0, %1, %2" : "=v"(j0) : "v"(p[0]),  "v"(p[1]));
            asm("v_cvt_pk_bf16_f32 %0, %1, %2" : "=v"(j1) : "v"(p[2]),  "v"(p[3]));
            asm("v_cvt_pk_bf16_f32 %0, %1, %2" : "=v"(j2) : "v"(p[4]),  "v"(p[5]));
            asm("v_cvt_pk_bf16_f32 %0, %1, %2" : "=v"(j3) : "v"(p[6]),  "v"(p[7]));
            asm("v_cvt_pk_bf16_f32 %0, %1, %2" : "=v"(j4) : "v"(p[8]),  "v"(p[9]));
            asm("v_cvt_pk_bf16_f32 %0, %1, %2" : "=v"(j5) : "v"(p[10]), "v"(p[11]));
            asm("v_cvt_pk_bf16_f32 %0, %1, %2" : "=v"(j6) : "v"(p[12]), "v"(p[13]));
            asm("v_cvt_pk_bf16_f32 %0, %1, %2" : "=v"(j7) : "v"(p[14]), "v"(p[15]));
            asm("v_permlane32_swap_b32 %0, %1" : "+v"(j0), "+v"(j2));
            asm("v_permlane32_swap_b32 %0, %1" : "+v"(j1), "+v"(j3));
            asm("v_permlane32_swap_b32 %0, %1" : "+v"(j4), "+v"(j6));
            asm("v_permlane32_swap_b32 %0, %1" : "+v"(j5), "+v"(j7));
            short8 pa0 = __builtin_bit_cast(short8, (uint4v){j0, j1, j2, j3});
            short8 pa1 = __builtin_bit_cast(short8, (uint4v){j4, j5, j6, j7});

            // PV: O[q][d] += P[q][k] * V[d][k]  (V as B-fragment)
            {
                int row = l31;                 // d 0..31
                short8 vf0 = *(const short8*)(&kvs[cur][1][row * 64 + (((ks * 4 + 0 + hf) ^ (row & 7)) * 8)]);
                short8 vf1 = *(const short8*)(&kvs[cur][1][row * 64 + (((ks * 4 + 2 + hf) ^ (row & 7)) * 8)]);
                __builtin_amdgcn_s_setprio(1);
                o0 = __builtin_amdgcn_mfma_f32_32x32x16_bf16(pa0, vf0, o0, 0, 0, 0);
                o0 = __builtin_amdgcn_mfma_f32_32x32x16_bf16(pa1, vf1, o0, 0, 0, 0);
                __builtin_amdgcn_s_setprio(0);
            }
            {
                int row = 32 + l31;            // d 32..63
                short8 vf0 = *(const short8*)(&kvs[cur][1][row * 64 + (((ks * 4 + 0 + hf) ^ (row & 7)) * 8)]);
                short8 vf1 = *(const short8*)(&kvs[cur][1][row * 64 + (((ks * 4 + 2 + hf) ^ (row & 7)) * 8)]);
                __builtin_amdgcn_s_setprio(1);
                o1 = __builtin_amdgcn_mfma_f32_32x32x16_bf16(pa0, vf0, o1, 0, 0, 0);
                o1 = __builtin_amdgcn_mfma_f32_32x32x16_bf16(pa1, vf1, o1, 0, 0, 0);
                __builtin_amdgcn_s_setprio(0);
            }
        }
    }

    // denominator: lanes l and l+32 hold partial sums for the same q=l31
    float tot = lsq + __shfl_xor(lsq, 32, 64);
    if (lane < 32) lsums[wv][l31] = 1.0f / tot;

#pragma unroll
    for (int r = 0; r < 16; ++r) {
        int qloc = (r & 3) + 8 * (r >> 2) + 4 * hf;
        float inv = lsums[wv][qloc];
        int q = qbase + qloc;
        float* orow = outp + ((size_t)b * SS + q) * EE + h * HD;
        __builtin_nontemporal_store(o0[r] * inv, orow + l31);
        __builtin_nontemporal_store(o1[r] * inv, orow + 32 + l31);
    }
}

extern "C" void kernel_launch(void* const* d_in, const int* in_sizes, int n_in,
                              void* d_out, int out_size, void* d_ws, size_t ws_size,
                              hipStream_t stream) {
    const float* X  = (const float*)d_in[0];
    const float* Wq = (const float*)d_in[1];
    const float* bq = (const float*)d_in[2];
    const float* Wk = (const float*)d_in[3];
    const float* bk = (const float*)d_in[4];
    const float* Wv = (const float*)d_in[5];
    const float* bv = (const float*)d_in[6];

    const size_t qkv_elems = (size_t)BB * NH * SS * HD;   // 8,388,608 bf16 each
    unsigned short* Qw = (unsigned short*)d_ws;
    unsigned short* Kw = Qw + qkv_elems;
    unsigned short* Vw = Kw + qkv_elems;

    unsigned short* cvt = (unsigned short*)d_out;
    const unsigned short* Xb = cvt;
    const unsigned short* WbAll = cvt + 8388608;

    cvt_kernel<<<dim3(11264), 256, 0, stream>>>(X, Wq, Wk, Wv, cvt);
    qkv_gemm4<<<dim3(1536), 256, 0, stream>>>(
        Xb, WbAll, bq, bk, bv, Qw, Kw, Vw);
    swa_kernel<<<dim3(1024), 256, 0, stream>>>(Qw, Kw, Vw, (float*)d_out);
}